// Round 14
// baseline (84.038 us; speedup 1.0000x reference)
//
#include <hip/hip_runtime.h>
#include <math.h>

typedef __fp16 h2 __attribute__((ext_vector_type(2)));
typedef __fp16 f16x8 __attribute__((ext_vector_type(8)));
typedef float f32x4 __attribute__((ext_vector_type(4)));

#define Bc 4
#define Lc 200
#define Hc 256
#define NHc 4
#define HSc 64
#define NBc 2
#define Mtot (Bc*Lc)   // 800
#define TROW 34        // LDS table row stride in u32 (68 halfs = 136B)
#define LDH 264        // mm LDS row stride in halves (528B)
#define WN (2*Hc*Hc)   // 131072 halves per weight array (both layers)
#define TN (257*Hc)    // 65792 halves per table

static __device__ __forceinline__ float neg_fill() { return -4294967295.0f; }
static __device__ __forceinline__ int rl(int x) { return __builtin_amdgcn_readfirstlane(x); }

static __device__ __forceinline__ uint pkh2(float a, float b) {
  h2 r = __builtin_amdgcn_cvt_pkrtz(a, b);
  return __builtin_bit_cast(uint, r);
}
static __device__ __forceinline__ h2 u2h(uint u) { return __builtin_bit_cast(h2, u); }
static __device__ __forceinline__ float h2f(ushort u) {
  return (float)__builtin_bit_cast(_Float16, u);
}

// ---------------- one-shot f32 -> f16 conversion of weights & tables --------
__global__ void cvtw_k(const float* __restrict__ Wq, const float* __restrict__ Wk,
                       const float* __restrict__ Wv, const float* __restrict__ W1,
                       const float* __restrict__ W2,
                       const float* __restrict__ tK, const float* __restrict__ tV,
                       const float* __restrict__ dK, const float* __restrict__ dV,
                       ushort* __restrict__ out) {
  int y = blockIdx.y;
  const float* src;
  int n, off;
  if (y < 5) {
    n = WN; off = y * WN;
    src = (y == 0) ? Wq : (y == 1) ? Wk : (y == 2) ? Wv : (y == 3) ? W1 : W2;
  } else {
    n = TN; off = 5 * WN + (y - 5) * TN;
    src = (y == 5) ? tK : (y == 6) ? tV : (y == 7) ? dK : dV;
  }
  int idx = (blockIdx.x * 256 + threadIdx.x) * 8;
  if (idx >= n) return;
  float4 a = *(const float4*)&src[idx];
  float4 b = *(const float4*)&src[idx + 4];
  uint4 o;
  o.x = pkh2(a.x, a.y); o.y = pkh2(a.z, a.w);
  o.z = pkh2(b.x, b.y); o.w = pkh2(b.z, b.w);
  *(uint4*)&out[off + idx] = o;
}

// ---------------- fused [embed+] LN1 + QKV projections (f16 weights) --------
// BM=32: grid (25, 12): y>>2 = region (0=Q,1=K,2=V), y&3 -> n-chunk of 64.
__global__ __launch_bounds__(256)
void mmqkv_k(const float* __restrict__ seqs, const float* __restrict__ emb,
             const int* __restrict__ logs, int useEmb,
             const float* __restrict__ g, const float* __restrict__ bt,
             const ushort* __restrict__ Wq16, const ushort* __restrict__ Wk16,
             const ushort* __restrict__ Wv16,
             const float* __restrict__ bq, const float* __restrict__ bk,
             const float* __restrict__ bv,
             const float* __restrict__ pK, const float* __restrict__ pV,
             float* __restrict__ Qn,
             ushort* __restrict__ Q16, ushort* __restrict__ K16,
             ushort* __restrict__ V16) {
  __shared__ __fp16 Al[32][LDH];
  __shared__ __fp16 Wl[64][LDH];
  int m0 = blockIdx.x * 32;
  int y = blockIdx.y;
  int region = y >> 2, nloc = (y & 3) * 64;
  const ushort* Wsrc = (region == 0) ? Wq16 : (region == 1 ? Wk16 : Wv16);
  const float* bias = (region == 0) ? bq : (region == 1 ? bk : bv);
  int t = threadIdx.x;
  if (region == 0) {
#pragma unroll
    for (int hh = 0; hh < 2; ++hh) {
      int r = hh * 16 + (t >> 4), c0 = (t & 15) * 16;
      int m = m0 + r;
      const float* xr;
      bool zero = false;
      if (useEmb) {
        int tok = logs[m];
        zero = (tok == 0);
        xr = &emb[tok * Hc + c0];
      } else {
        xr = &seqs[m * Hc + c0];
      }
      float4 v0, v1, v2, v3;
      if (zero) {
        v0 = v1 = v2 = v3 = make_float4(0.f, 0.f, 0.f, 0.f);
      } else {
        v0 = *(const float4*)&xr[0];
        v1 = *(const float4*)&xr[4];
        v2 = *(const float4*)&xr[8];
        v3 = *(const float4*)&xr[12];
      }
      float s = v0.x + v0.y + v0.z + v0.w + v1.x + v1.y + v1.z + v1.w
              + v2.x + v2.y + v2.z + v2.w + v3.x + v3.y + v3.z + v3.w;
      float q = v0.x*v0.x + v0.y*v0.y + v0.z*v0.z + v0.w*v0.w
              + v1.x*v1.x + v1.y*v1.y + v1.z*v1.z + v1.w*v1.w
              + v2.x*v2.x + v2.y*v2.y + v2.z*v2.z + v2.w*v2.w
              + v3.x*v3.x + v3.y*v3.y + v3.z*v3.z + v3.w*v3.w;
#pragma unroll
      for (int o = 1; o < 16; o <<= 1) { s += __shfl_xor(s, o); q += __shfl_xor(q, o); }
      float mean = s * (1.f / Hc);
      float var = q * (1.f / Hc) - mean * mean;
      float rstd = 1.f / sqrtf(var + 1e-8f);
      float tmp[16] = {v0.x,v0.y,v0.z,v0.w,v1.x,v1.y,v1.z,v1.w,
                       v2.x,v2.y,v2.z,v2.w,v3.x,v3.y,v3.z,v3.w};
      float nv[16];
#pragma unroll
      for (int j = 0; j < 16; ++j)
        nv[j] = (tmp[j] - mean) * rstd * g[c0 + j] + bt[c0 + j];
#pragma unroll
      for (int j = 0; j < 16; j += 2)
        *(h2*)&Al[r][c0 + j] = __builtin_amdgcn_cvt_pkrtz(nv[j], nv[j + 1]);
      if (y == 0) {
#pragma unroll
        for (int j = 0; j < 16; j += 4)
          *(float4*)&Qn[m * Hc + c0 + j] = make_float4(nv[j], nv[j+1], nv[j+2], nv[j+3]);
      }
    }
  } else {
    for (int i = t; i < 32 * 64; i += 256) {
      int r = i >> 6, c = (i & 63) * 4;
      int m = m0 + r;
      float4 v;
      if (useEmb) {
        int tok = logs[m];
        v = (tok == 0) ? make_float4(0.f, 0.f, 0.f, 0.f)
                       : *(const float4*)&emb[tok * Hc + c];
      } else {
        v = *(const float4*)&seqs[m * Hc + c];
      }
      *(h2*)&Al[r][c] = __builtin_amdgcn_cvt_pkrtz(v.x, v.y);
      *(h2*)&Al[r][c + 2] = __builtin_amdgcn_cvt_pkrtz(v.z, v.w);
    }
  }
  for (int i = t; i < 2048; i += 256) {
    int r = i >> 5, c = (i & 31) * 8;
    uint4 v = *(const uint4*)&Wsrc[(nloc + r) * Hc + c];
    *(uint4*)&Wl[r][c] = v;
  }
  __syncthreads();
  int wave = t >> 6, lane = t & 63;
  int row = lane & 15, kg = lane >> 4;
  int bn = wave * 16 + row;
  f32x4 acc0 = {0.f, 0.f, 0.f, 0.f};
  f32x4 acc1 = {0.f, 0.f, 0.f, 0.f};
#pragma unroll
  for (int k0 = 0; k0 < Hc; k0 += 32) {
    int kk = k0 + kg * 8;
    f16x8 bb = *(const f16x8*)&Wl[bn][kk];
    f16x8 a0 = *(const f16x8*)&Al[row][kk];
    f16x8 a1 = *(const f16x8*)&Al[16 + row][kk];
    acc0 = __builtin_amdgcn_mfma_f32_16x16x32_f16(a0, bb, acc0, 0, 0, 0);
    acc1 = __builtin_amdgcn_mfma_f32_16x16x32_f16(a1, bb, acc1, 0, 0, 0);
  }
  int coln = nloc + wave * 16 + row;
  ushort* op = (region == 0) ? Q16 : (region == 1 ? K16 : V16);
  const float* pT = (region == 1) ? pK : pV;
  float bcol = bias[coln];
#pragma unroll
  for (int r = 0; r < 4; ++r) {
    int ma = m0 + kg * 4 + r;
    int mb = ma + 16;
    float va = acc0[r] + bcol;
    float vb = acc1[r] + bcol;
    if (region) {
      va += pT[(ma % Lc) * Hc + coln];
      vb += pT[(mb % Lc) * Hc + coln];
    }
    op[ma * Hc + coln] = __builtin_bit_cast(ushort, (_Float16)va);
    op[mb * Hc + coln] = __builtin_bit_cast(ushort, (_Float16)vb);
  }
}

// ---------------- fused attention: MFMA scores + softmax + paired-k out -----
// grid (NHc, Bc, 16) = 256 blocks; block 1024 (16 waves), wave w owns q=16w+bz.
// tV staged in LDS; dV gathered from L2 (coalesced 128B row segments).
__global__ __launch_bounds__(1024, 4)
void attn_k(const ushort* __restrict__ Q16, const ushort* __restrict__ K16,
            const ushort* __restrict__ V16,
            const ushort* __restrict__ tK16, const ushort* __restrict__ dK16,
            const ushort* __restrict__ tV16, const ushort* __restrict__ dV16,
            const int* __restrict__ tm, const int* __restrict__ dm,
            const int* __restrict__ logs,
            const float* __restrict__ Qn, float* __restrict__ seqs) {
  int h = blockIdx.x, b = blockIdx.y, bz = blockIdx.z;
  __shared__ uint tVs[257 * TROW];
  __shared__ float S0l[16][212];
  __shared__ float Tql[16][272];
  __shared__ float Dql[16][272];
  __shared__ float sArow[16][204];
  int t = threadIdx.x;
  int wave = t >> 6, lane = t & 63;
  int row16 = lane & 15, kg = lane >> 4;
  // ---- stage tV (out-phase table) ----
  {
    const ushort* s1 = tV16 + h * HSc;
    for (int i = t; i < 257 * 8; i += 1024) {
      int r = i >> 3, c = (i & 7) * 8;
      *(uint4*)&tVs[r * TROW + (c >> 1)] = *(const uint4*)&s1[r * Hc + c];
    }
  }
  // ---- phase 1: MFMA tile-jobs ----
  {
    int qa = row16 * 16 + bz;               // A-row (strided q of this block)
    bool va = qa < Lc;
    f16x8 A0 = {0,0,0,0,0,0,0,0}, A1 = A0;
    if (va) {
      const ushort* Qr = &Q16[(b * Lc + qa) * Hc + h * HSc];
      A0 = *(const f16x8*)&Qr[kg * 8];
      A1 = *(const f16x8*)&Qr[32 + kg * 8];
    }
    for (int j = wave; j < 47; j += 16) {
      int kind, n;
      if (j < 13) { kind = 0; n = j; }
      else if (j < 30) { kind = 1; n = j - 13; }
      else { kind = 2; n = j - 30; }
      int col = n * 16 + row16;
      const ushort* Bsrc;
      bool vb;
      if (kind == 0) { vb = col < Lc; Bsrc = &K16[(b * Lc + (vb ? col : 0)) * Hc + h * HSc]; }
      else { vb = col < 257; Bsrc = &((kind == 1) ? tK16 : dK16)[(vb ? col : 0) * Hc + h * HSc]; }
      f16x8 B0 = {0,0,0,0,0,0,0,0}, B1 = B0;
      if (vb) {
        B0 = *(const f16x8*)&Bsrc[kg * 8];
        B1 = *(const f16x8*)&Bsrc[32 + kg * 8];
      }
      f32x4 acc = {0.f, 0.f, 0.f, 0.f};
      acc = __builtin_amdgcn_mfma_f32_16x16x32_f16(A0, B0, acc, 0, 0, 0);
      acc = __builtin_amdgcn_mfma_f32_16x16x32_f16(A1, B1, acc, 0, 0, 0);
      if (kind == 0) {
#pragma unroll
        for (int r = 0; r < 4; ++r) S0l[kg * 4 + r][col] = acc[r];
      } else if (kind == 1) {
#pragma unroll
        for (int r = 0; r < 4; ++r) Tql[kg * 4 + r][col] = acc[r];
      } else {
#pragma unroll
        for (int r = 0; r < 4; ++r) Dql[kg * 4 + r][col] = acc[r];
      }
    }
  }
  __syncthreads();
  // ---- phase 2: per-wave score assembly + softmax + output ----
  int q = wave * 16 + bz;
  if (q >= Lc) return;
  int m = b * Lc + q;
  int oi = m * Hc + h * HSc + lane;
  if (logs[m] == 0) { seqs[oi] = Qn[oi]; return; }
  const int* tmr = tm + rl(m * Lc);
  const int* dmr = dm + rl(m * Lc);
  const float* srow = S0l[wave];
  const float* trow = Tql[wave];
  const float* drow = Dql[wave];
  int np = (q >> 6) + 1;
  float sv[4];
  float mx = neg_fill();
#pragma unroll
  for (int p = 0; p < 4; ++p) {
    sv[p] = neg_fill();
    if (p >= np) continue;
    int k = p * 64 + lane;
    int kc = (k <= q) ? k : q;
    int ti = tmr[kc], di = dmr[kc];
    float sc = (srow[kc] + trow[ti] + drow[di]) * 0.125f;
    if (k <= q) sv[p] = sc;
    mx = fmaxf(mx, sv[p]);
  }
#pragma unroll
  for (int o = 32; o; o >>= 1) mx = fmaxf(mx, __shfl_xor(mx, o));
  float sum = 0.f;
  float ev[4];
#pragma unroll
  for (int p = 0; p < 4; ++p) {
    ev[p] = __expf(sv[p] - mx);
    sum += ev[p];
  }
#pragma unroll
  for (int o = 32; o; o >>= 1) sum += __shfl_xor(sum, o);
  float rs = 1.f / sum;
#pragma unroll
  for (int p = 0; p < 4; ++p) {
    if (p >= np) continue;
    int k = p * 64 + lane;
    if (k < Lc) sArow[wave][k] = ev[p] * rs;
  }
  for (int k = q + 1 + lane; k < 204; k += 64) sArow[wave][k] = 0.f;
  int half = lane >> 5, li = lane & 31;
  const uint* Vu  = (const uint*)V16 + rl(b * Lc * (Hc / 2) + h * (HSc / 2)) + li;
  const uint* dVg = (const uint*)dV16 + rl(h * (HSc / 2)) + li;
  float acc0 = 0.f, acc1 = 0.f, acc2 = 0.f, acc3 = 0.f;
#pragma unroll 2
  for (int k0 = 0; k0 <= q; k0 += 4) {
    int ka = k0 + half;
    int kb = k0 + 2 + half;
    int kca = (ka <= q) ? ka : q;
    int kcb = (kb <= q) ? kb : q;
    float aa = sArow[wave][ka];
    float ab = sArow[wave][kb];
    int ti0 = tmr[kca], di0 = dmr[kca];
    int ti1 = tmr[kcb], di1 = dmr[kcb];
    uint tv0 = tVs[ti0 * TROW + li];
    uint dv0 = dVg[di0 * (Hc / 2)];
    uint vv0 = Vu[kca * (Hc / 2)];
    uint tv1 = tVs[ti1 * TROW + li];
    uint dv1 = dVg[di1 * (Hc / 2)];
    uint vv1 = Vu[kcb * (Hc / 2)];
    h2 s0 = u2h(tv0) + u2h(dv0) + u2h(vv0);
    h2 s1 = u2h(tv1) + u2h(dv1) + u2h(vv1);
    acc0 = fmaf(aa, (float)s0.x, acc0);
    acc1 = fmaf(aa, (float)s0.y, acc1);
    acc2 = fmaf(ab, (float)s1.x, acc2);
    acc3 = fmaf(ab, (float)s1.y, acc3);
  }
  float accLo = acc0 + acc2; accLo += __shfl_xor(accLo, 32);
  float accHi = acc1 + acc3; accHi += __shfl_xor(accHi, 32);
  if (half == 0) {
    int oib = m * Hc + h * HSc + 2 * li;
    float2 qv = *(const float2*)&Qn[oib];
    float2 r;
    r.x = qv.x + accLo;
    r.y = qv.y + accHi;
    *(float2*)&seqs[oib] = r;
  }
}

// ---------------- fused LN2 + FFN1(relu) + FFN2 + residual + keep [+ lnf] ---
template <int FIN>
__global__ __launch_bounds__(512)
void ffn_k(float* __restrict__ seqs,
           const float* __restrict__ g, const float* __restrict__ bt,
           const ushort* __restrict__ W1_16, const float* __restrict__ b1,
           const ushort* __restrict__ W2_16, const float* __restrict__ b2,
           const int* __restrict__ logs,
           const float* __restrict__ lnf_g, const float* __restrict__ lnf_b,
           float* __restrict__ dout) {
  __shared__ __fp16 Xl[16][LDH];
  __shared__ __fp16 Hl[16][LDH];
  __shared__ __fp16 Wl[128][LDH];
  __shared__ float Ol[16][Hc];
  int m0 = blockIdx.x * 16;
  int t = threadIdx.x;
  {
    int r = t >> 5, c0 = (t & 31) * 8;
    const float* xr = &seqs[(m0 + r) * Hc + c0];
    float4 v0 = *(const float4*)&xr[0];
    float4 v1 = *(const float4*)&xr[4];
    float s = v0.x + v0.y + v0.z + v0.w + v1.x + v1.y + v1.z + v1.w;
    float q = v0.x*v0.x + v0.y*v0.y + v0.z*v0.z + v0.w*v0.w
            + v1.x*v1.x + v1.y*v1.y + v1.z*v1.z + v1.w*v1.w;
#pragma unroll
    for (int o = 1; o < 32; o <<= 1) { s += __shfl_xor(s, o); q += __shfl_xor(q, o); }
    float mean = s * (1.f / Hc);
    float var = q * (1.f / Hc) - mean * mean;
    float rstd = 1.f / sqrtf(var + 1e-8f);
    float tmp[8] = {v0.x,v0.y,v0.z,v0.w,v1.x,v1.y,v1.z,v1.w};
    float nv[8];
#pragma unroll
    for (int j = 0; j < 8; ++j)
      nv[j] = (tmp[j] - mean) * rstd * g[c0 + j] + bt[c0 + j];
#pragma unroll
    for (int j = 0; j < 8; j += 2)
      *(h2*)&Xl[r][c0 + j] = __builtin_amdgcn_cvt_pkrtz(nv[j], nv[j + 1]);
  }
  int wave = t >> 6, lane = t & 63;
  int row = lane & 15, kg = lane >> 4;
#pragma unroll
  for (int ch = 0; ch < 2; ++ch) {
    __syncthreads();
    for (int i = t; i < 4096; i += 512) {
      int r = i >> 5, c = (i & 31) * 8;
      uint4 v = *(const uint4*)&W1_16[(ch * 128 + r) * Hc + c];
      *(uint4*)&Wl[r][c] = v;
    }
    __syncthreads();
    int bn = wave * 16 + row;
    f32x4 acc = {0.f, 0.f, 0.f, 0.f};
#pragma unroll
    for (int k0 = 0; k0 < Hc; k0 += 32) {
      int kk = k0 + kg * 8;
      f16x8 a = *(const f16x8*)&Xl[row][kk];
      f16x8 bb = *(const f16x8*)&Wl[bn][kk];
      acc = __builtin_amdgcn_mfma_f32_16x16x32_f16(a, bb, acc, 0, 0, 0);
    }
    int coln = ch * 128 + wave * 16 + row;
    float bv = b1[coln];
#pragma unroll
    for (int r = 0; r < 4; ++r) {
      float v = fmaxf(acc[r] + bv, 0.f);
      Hl[kg * 4 + r][coln] = (_Float16)v;
    }
  }
#pragma unroll
  for (int ch = 0; ch < 2; ++ch) {
    __syncthreads();
    for (int i = t; i < 4096; i += 512) {
      int r = i >> 5, c = (i & 31) * 8;
      uint4 v = *(const uint4*)&W2_16[(ch * 128 + r) * Hc + c];
      *(uint4*)&Wl[r][c] = v;
    }
    __syncthreads();
    int bn = wave * 16 + row;
    f32x4 acc = {0.f, 0.f, 0.f, 0.f};
#pragma unroll
    for (int k0 = 0; k0 < Hc; k0 += 32) {
      int kk = k0 + kg * 8;
      f16x8 a = *(const f16x8*)&Hl[row][kk];
      f16x8 bb = *(const f16x8*)&Wl[bn][kk];
      acc = __builtin_amdgcn_mfma_f32_16x16x32_f16(a, bb, acc, 0, 0, 0);
    }
    int coln = ch * 128 + wave * 16 + row;
    float bv = b2[coln];
#pragma unroll
    for (int r = 0; r < 4; ++r) {
      int mrow = kg * 4 + r;
      int m = m0 + mrow;
      float keep = (logs[m] != 0) ? 1.f : 0.f;
      float xv = h2f(__builtin_bit_cast(ushort, Xl[mrow][coln]));
      float val = (acc[r] + bv + xv) * keep;
      if (FIN) Ol[mrow][coln] = val;
      else     seqs[m * Hc + coln] = val;
    }
  }
  if (FIN) {
    __syncthreads();
    int r = t >> 5, c0 = (t & 31) * 8;
    float v[8];
#pragma unroll
    for (int j = 0; j < 8; ++j) v[j] = Ol[r][c0 + j];
    float s = 0.f, q = 0.f;
#pragma unroll
    for (int j = 0; j < 8; ++j) { s += v[j]; q += v[j] * v[j]; }
#pragma unroll
    for (int o = 1; o < 32; o <<= 1) { s += __shfl_xor(s, o); q += __shfl_xor(q, o); }
    float mean = s * (1.f / Hc);
    float var = q * (1.f / Hc) - mean * mean;
    float rstd = 1.f / sqrtf(var + 1e-8f);
#pragma unroll
    for (int j = 0; j < 8; ++j)
      dout[(m0 + r) * Hc + c0 + j] = (v[j] - mean) * rstd * lnf_g[c0 + j] + lnf_b[c0 + j];
  }
}

extern "C" void kernel_launch(void* const* d_in, const int* in_sizes, int n_in,
                              void* d_out, int out_size, void* d_ws, size_t ws_size,
                              hipStream_t stream) {
  const int* logs = (const int*)d_in[0];
  const int* tm   = (const int*)d_in[1];
  const int* dm   = (const int*)d_in[2];
  const float* item = (const float*)d_in[3];
  const float* pK = (const float*)d_in[4];
  const float* pV = (const float*)d_in[5];
  const float* tK = (const float*)d_in[6];
  const float* tV = (const float*)d_in[7];
  const float* dK = (const float*)d_in[8];
  const float* dV = (const float*)d_in[9];
  const float* ln1_g = (const float*)d_in[10];
  const float* ln1_b = (const float*)d_in[11];
  const float* Wq = (const float*)d_in[12];
  const float* bq = (const float*)d_in[13];
  const float* Wk = (const float*)d_in[14];
  const float* bk = (const float*)d_in[15];
  const float* Wv = (const float*)d_in[16];
  const float* bv = (const float*)d_in[17];
  const float* ln2_g = (const float*)d_in[18];
  const float* ln2_b = (const float*)d_in[19];
  const float* W1 = (const float*)d_in[20];
  const float* b1 = (const float*)d_in[21];
  const float* W2 = (const float*)d_in[22];
  const float* b2 = (const float*)d_in[23];
  const float* lnf_g = (const float*)d_in[24];
  const float* lnf_b = (const float*)d_in[25];

  const int NROW = Mtot * Hc;          // 204800 floats
  float* ws = (float*)d_ws;
  float* sSeqs = ws + 0 * NROW;
  float* sQn   = ws + 1 * NROW;
  ushort* Q16  = (ushort*)(ws + 2 * NROW);
  ushort* K16  = Q16 + NROW;
  ushort* V16  = K16 + NROW;
  ushort* w16  = (ushort*)(ws + 4 * NROW);   // 5*WN + 4*TN halves
  ushort* wq16 = w16 + 0 * WN;
  ushort* wk16 = w16 + 1 * WN;
  ushort* wv16 = w16 + 2 * WN;
  ushort* w116 = w16 + 3 * WN;
  ushort* w216 = w16 + 4 * WN;
  ushort* tK16 = w16 + 5 * WN;
  ushort* tV16 = tK16 + TN;
  ushort* dK16 = tV16 + TN;
  ushort* dV16 = dK16 + TN;

  dim3 gC(64, 9);
  cvtw_k<<<gC, 256, 0, stream>>>(Wq, Wk, Wv, W1, W2, tK, tV, dK, dV, w16);

  dim3 gQKV(Mtot / 32, 12);
  dim3 ga(NHc, Bc, 16);
  const int HHh = Hc * Hc;
  for (int i = 0; i < NBc; ++i) {
    mmqkv_k<<<gQKV, 256, 0, stream>>>(sSeqs, item, logs, (i == 0) ? 1 : 0,
                                      ln1_g + i * Hc, ln1_b + i * Hc,
                                      wq16 + i * HHh, wk16 + i * HHh, wv16 + i * HHh,
                                      bq + i * Hc, bk + i * Hc, bv + i * Hc,
                                      pK, pV, sQn, Q16, K16, V16);
    attn_k<<<ga, 1024, 0, stream>>>(Q16, K16, V16,
                                    tK16, dK16, tV16, dV16,
                                    tm, dm, logs, sQn, sSeqs);
    if (i == 0)
      ffn_k<0><<<Mtot / 16, 512, 0, stream>>>(sSeqs, ln2_g + i * Hc, ln2_b + i * Hc,
                                              w116 + i * HHh, b1 + i * Hc,
                                              w216 + i * HHh, b2 + i * Hc, logs,
                                              nullptr, nullptr, nullptr);
    else
      ffn_k<1><<<Mtot / 16, 512, 0, stream>>>(sSeqs, ln2_g + i * Hc, ln2_b + i * Hc,
                                              w116 + i * HHh, b1 + i * Hc,
                                              w216 + i * HHh, b2 + i * Hc, logs,
                                              lnf_g, lnf_b, (float*)d_out);
  }
}

// Round 15
// 80.632 us; speedup vs baseline: 1.0422x; 1.0422x over previous
//
#include <hip/hip_runtime.h>
#include <math.h>

typedef __fp16 h2 __attribute__((ext_vector_type(2)));
typedef __fp16 f16x8 __attribute__((ext_vector_type(8)));
typedef float f32x4 __attribute__((ext_vector_type(4)));

#define Bc 4
#define Lc 200
#define Hc 256
#define NHc 4
#define HSc 64
#define NBc 2
#define Mtot (Bc*Lc)   // 800
#define TROW 34        // LDS table row stride in u32 (68 halfs = 136B)
#define LDH 264        // mm LDS row stride in halves (528B)
#define WN (2*Hc*Hc)   // 131072 halves per weight array (both layers)
#define TN (257*Hc)    // 65792 halves per table

static __device__ __forceinline__ float neg_fill() { return -4294967295.0f; }
static __device__ __forceinline__ int rl(int x) { return __builtin_amdgcn_readfirstlane(x); }

static __device__ __forceinline__ uint pkh2(float a, float b) {
  h2 r = __builtin_amdgcn_cvt_pkrtz(a, b);
  return __builtin_bit_cast(uint, r);
}
static __device__ __forceinline__ h2 u2h(uint u) { return __builtin_bit_cast(h2, u); }
static __device__ __forceinline__ float h2f(ushort u) {
  return (float)__builtin_bit_cast(_Float16, u);
}

// ---------------- one-shot f32 -> f16 conversion of weights & tables --------
__global__ void cvtw_k(const float* __restrict__ Wq, const float* __restrict__ Wk,
                       const float* __restrict__ Wv, const float* __restrict__ W1,
                       const float* __restrict__ W2,
                       const float* __restrict__ tK, const float* __restrict__ tV,
                       const float* __restrict__ dK, const float* __restrict__ dV,
                       ushort* __restrict__ out) {
  int y = blockIdx.y;
  const float* src;
  int n, off;
  if (y < 5) {
    n = WN; off = y * WN;
    src = (y == 0) ? Wq : (y == 1) ? Wk : (y == 2) ? Wv : (y == 3) ? W1 : W2;
  } else {
    n = TN; off = 5 * WN + (y - 5) * TN;
    src = (y == 5) ? tK : (y == 6) ? tV : (y == 7) ? dK : dV;
  }
  int idx = (blockIdx.x * 256 + threadIdx.x) * 8;
  if (idx >= n) return;
  float4 a = *(const float4*)&src[idx];
  float4 b = *(const float4*)&src[idx + 4];
  uint4 o;
  o.x = pkh2(a.x, a.y); o.y = pkh2(a.z, a.w);
  o.z = pkh2(b.x, b.y); o.w = pkh2(b.z, b.w);
  *(uint4*)&out[off + idx] = o;
}

// ---------------- fused [embed+] LN1 + QKV projections (f16 weights) --------
// BM=32: grid (25, 12): y>>2 = region (0=Q,1=K,2=V), y&3 -> n-chunk of 64.
__global__ __launch_bounds__(256)
void mmqkv_k(const float* __restrict__ seqs, const float* __restrict__ emb,
             const int* __restrict__ logs, int useEmb,
             const float* __restrict__ g, const float* __restrict__ bt,
             const ushort* __restrict__ Wq16, const ushort* __restrict__ Wk16,
             const ushort* __restrict__ Wv16,
             const float* __restrict__ bq, const float* __restrict__ bk,
             const float* __restrict__ bv,
             const float* __restrict__ pK, const float* __restrict__ pV,
             float* __restrict__ Qn,
             ushort* __restrict__ Q16, ushort* __restrict__ K16,
             ushort* __restrict__ V16) {
  __shared__ __fp16 Al[32][LDH];
  __shared__ __fp16 Wl[64][LDH];
  int m0 = blockIdx.x * 32;
  int y = blockIdx.y;
  int region = y >> 2, nloc = (y & 3) * 64;
  const ushort* Wsrc = (region == 0) ? Wq16 : (region == 1 ? Wk16 : Wv16);
  const float* bias = (region == 0) ? bq : (region == 1 ? bk : bv);
  int t = threadIdx.x;
  if (region == 0) {
#pragma unroll
    for (int hh = 0; hh < 2; ++hh) {
      int r = hh * 16 + (t >> 4), c0 = (t & 15) * 16;
      int m = m0 + r;
      const float* xr;
      bool zero = false;
      if (useEmb) {
        int tok = logs[m];
        zero = (tok == 0);
        xr = &emb[tok * Hc + c0];
      } else {
        xr = &seqs[m * Hc + c0];
      }
      float4 v0, v1, v2, v3;
      if (zero) {
        v0 = v1 = v2 = v3 = make_float4(0.f, 0.f, 0.f, 0.f);
      } else {
        v0 = *(const float4*)&xr[0];
        v1 = *(const float4*)&xr[4];
        v2 = *(const float4*)&xr[8];
        v3 = *(const float4*)&xr[12];
      }
      float s = v0.x + v0.y + v0.z + v0.w + v1.x + v1.y + v1.z + v1.w
              + v2.x + v2.y + v2.z + v2.w + v3.x + v3.y + v3.z + v3.w;
      float q = v0.x*v0.x + v0.y*v0.y + v0.z*v0.z + v0.w*v0.w
              + v1.x*v1.x + v1.y*v1.y + v1.z*v1.z + v1.w*v1.w
              + v2.x*v2.x + v2.y*v2.y + v2.z*v2.z + v2.w*v2.w
              + v3.x*v3.x + v3.y*v3.y + v3.z*v3.z + v3.w*v3.w;
#pragma unroll
      for (int o = 1; o < 16; o <<= 1) { s += __shfl_xor(s, o); q += __shfl_xor(q, o); }
      float mean = s * (1.f / Hc);
      float var = q * (1.f / Hc) - mean * mean;
      float rstd = 1.f / sqrtf(var + 1e-8f);
      float tmp[16] = {v0.x,v0.y,v0.z,v0.w,v1.x,v1.y,v1.z,v1.w,
                       v2.x,v2.y,v2.z,v2.w,v3.x,v3.y,v3.z,v3.w};
      float nv[16];
#pragma unroll
      for (int j = 0; j < 16; ++j)
        nv[j] = (tmp[j] - mean) * rstd * g[c0 + j] + bt[c0 + j];
#pragma unroll
      for (int j = 0; j < 16; j += 2)
        *(h2*)&Al[r][c0 + j] = __builtin_amdgcn_cvt_pkrtz(nv[j], nv[j + 1]);
      if (y == 0) {
#pragma unroll
        for (int j = 0; j < 16; j += 4)
          *(float4*)&Qn[m * Hc + c0 + j] = make_float4(nv[j], nv[j+1], nv[j+2], nv[j+3]);
      }
    }
  } else {
    for (int i = t; i < 32 * 64; i += 256) {
      int r = i >> 6, c = (i & 63) * 4;
      int m = m0 + r;
      float4 v;
      if (useEmb) {
        int tok = logs[m];
        v = (tok == 0) ? make_float4(0.f, 0.f, 0.f, 0.f)
                       : *(const float4*)&emb[tok * Hc + c];
      } else {
        v = *(const float4*)&seqs[m * Hc + c];
      }
      *(h2*)&Al[r][c] = __builtin_amdgcn_cvt_pkrtz(v.x, v.y);
      *(h2*)&Al[r][c + 2] = __builtin_amdgcn_cvt_pkrtz(v.z, v.w);
    }
  }
  for (int i = t; i < 2048; i += 256) {
    int r = i >> 5, c = (i & 31) * 8;
    uint4 v = *(const uint4*)&Wsrc[(nloc + r) * Hc + c];
    *(uint4*)&Wl[r][c] = v;
  }
  __syncthreads();
  int wave = t >> 6, lane = t & 63;
  int row = lane & 15, kg = lane >> 4;
  int bn = wave * 16 + row;
  f32x4 acc0 = {0.f, 0.f, 0.f, 0.f};
  f32x4 acc1 = {0.f, 0.f, 0.f, 0.f};
#pragma unroll
  for (int k0 = 0; k0 < Hc; k0 += 32) {
    int kk = k0 + kg * 8;
    f16x8 bb = *(const f16x8*)&Wl[bn][kk];
    f16x8 a0 = *(const f16x8*)&Al[row][kk];
    f16x8 a1 = *(const f16x8*)&Al[16 + row][kk];
    acc0 = __builtin_amdgcn_mfma_f32_16x16x32_f16(a0, bb, acc0, 0, 0, 0);
    acc1 = __builtin_amdgcn_mfma_f32_16x16x32_f16(a1, bb, acc1, 0, 0, 0);
  }
  int coln = nloc + wave * 16 + row;
  ushort* op = (region == 0) ? Q16 : (region == 1 ? K16 : V16);
  const float* pT = (region == 1) ? pK : pV;
  float bcol = bias[coln];
#pragma unroll
  for (int r = 0; r < 4; ++r) {
    int ma = m0 + kg * 4 + r;
    int mb = ma + 16;
    float va = acc0[r] + bcol;
    float vb = acc1[r] + bcol;
    if (region) {
      va += pT[(ma % Lc) * Hc + coln];
      vb += pT[(mb % Lc) * Hc + coln];
    }
    op[ma * Hc + coln] = __builtin_bit_cast(ushort, (_Float16)va);
    op[mb * Hc + coln] = __builtin_bit_cast(ushort, (_Float16)vb);
  }
}

// ---------------- fused attention: MFMA scores + softmax + paired-k out -----
// grid (NHc, Bc, 16) = 256 blocks; block 1024 (16 waves), wave w owns q=16w+bz.
// Round-13 verified version: tV+dV staged in LDS, launch_bounds(1024,4).
__global__ __launch_bounds__(1024, 4)
void attn_k(const ushort* __restrict__ Q16, const ushort* __restrict__ K16,
            const ushort* __restrict__ V16,
            const ushort* __restrict__ tK16, const ushort* __restrict__ dK16,
            const ushort* __restrict__ tV16, const ushort* __restrict__ dV16,
            const int* __restrict__ tm, const int* __restrict__ dm,
            const int* __restrict__ logs,
            const float* __restrict__ Qn, float* __restrict__ seqs) {
  int h = blockIdx.x, b = blockIdx.y, bz = blockIdx.z;
  __shared__ uint tVs[257 * TROW];
  __shared__ uint dVs[257 * TROW];
  __shared__ float S0l[16][212];
  __shared__ float Tql[16][272];
  __shared__ float Dql[16][272];
  __shared__ float sArow[16][204];
  int t = threadIdx.x;
  int wave = t >> 6, lane = t & 63;
  int row16 = lane & 15, kg = lane >> 4;
  // ---- stage tV/dV (out-phase tables) ----
  {
    const ushort* s1 = tV16 + h * HSc;
    const ushort* s2 = dV16 + h * HSc;
    for (int i = t; i < 257 * 8; i += 1024) {
      int r = i >> 3, c = (i & 7) * 8;
      *(uint4*)&tVs[r * TROW + (c >> 1)] = *(const uint4*)&s1[r * Hc + c];
      *(uint4*)&dVs[r * TROW + (c >> 1)] = *(const uint4*)&s2[r * Hc + c];
    }
  }
  // ---- phase 1: MFMA tile-jobs ----
  {
    int qa = row16 * 16 + bz;               // A-row (strided q of this block)
    bool va = qa < Lc;
    f16x8 A0 = {0,0,0,0,0,0,0,0}, A1 = A0;
    if (va) {
      const ushort* Qr = &Q16[(b * Lc + qa) * Hc + h * HSc];
      A0 = *(const f16x8*)&Qr[kg * 8];
      A1 = *(const f16x8*)&Qr[32 + kg * 8];
    }
    for (int j = wave; j < 47; j += 16) {
      int kind, n;
      if (j < 13) { kind = 0; n = j; }
      else if (j < 30) { kind = 1; n = j - 13; }
      else { kind = 2; n = j - 30; }
      int col = n * 16 + row16;
      const ushort* Bsrc;
      bool vb;
      if (kind == 0) { vb = col < Lc; Bsrc = &K16[(b * Lc + (vb ? col : 0)) * Hc + h * HSc]; }
      else { vb = col < 257; Bsrc = &((kind == 1) ? tK16 : dK16)[(vb ? col : 0) * Hc + h * HSc]; }
      f16x8 B0 = {0,0,0,0,0,0,0,0}, B1 = B0;
      if (vb) {
        B0 = *(const f16x8*)&Bsrc[kg * 8];
        B1 = *(const f16x8*)&Bsrc[32 + kg * 8];
      }
      f32x4 acc = {0.f, 0.f, 0.f, 0.f};
      acc = __builtin_amdgcn_mfma_f32_16x16x32_f16(A0, B0, acc, 0, 0, 0);
      acc = __builtin_amdgcn_mfma_f32_16x16x32_f16(A1, B1, acc, 0, 0, 0);
      if (kind == 0) {
#pragma unroll
        for (int r = 0; r < 4; ++r) S0l[kg * 4 + r][col] = acc[r];
      } else if (kind == 1) {
#pragma unroll
        for (int r = 0; r < 4; ++r) Tql[kg * 4 + r][col] = acc[r];
      } else {
#pragma unroll
        for (int r = 0; r < 4; ++r) Dql[kg * 4 + r][col] = acc[r];
      }
    }
  }
  __syncthreads();
  // ---- phase 2: per-wave score assembly + softmax + output ----
  int q = wave * 16 + bz;
  if (q >= Lc) return;
  int m = b * Lc + q;
  int oi = m * Hc + h * HSc + lane;
  if (logs[m] == 0) { seqs[oi] = Qn[oi]; return; }
  const int* tmr = tm + rl(m * Lc);
  const int* dmr = dm + rl(m * Lc);
  const float* srow = S0l[wave];
  const float* trow = Tql[wave];
  const float* drow = Dql[wave];
  int np = (q >> 6) + 1;
  float sv[4];
  float mx = neg_fill();
#pragma unroll
  for (int p = 0; p < 4; ++p) {
    sv[p] = neg_fill();
    if (p >= np) continue;
    int k = p * 64 + lane;
    int kc = (k <= q) ? k : q;
    int ti = tmr[kc], di = dmr[kc];
    float sc = (srow[kc] + trow[ti] + drow[di]) * 0.125f;
    if (k <= q) sv[p] = sc;
    mx = fmaxf(mx, sv[p]);
  }
#pragma unroll
  for (int o = 32; o; o >>= 1) mx = fmaxf(mx, __shfl_xor(mx, o));
  float sum = 0.f;
  float ev[4];
#pragma unroll
  for (int p = 0; p < 4; ++p) {
    ev[p] = __expf(sv[p] - mx);
    sum += ev[p];
  }
#pragma unroll
  for (int o = 32; o; o >>= 1) sum += __shfl_xor(sum, o);
  float rs = 1.f / sum;
#pragma unroll
  for (int p = 0; p < 4; ++p) {
    if (p >= np) continue;
    int k = p * 64 + lane;
    if (k < Lc) sArow[wave][k] = ev[p] * rs;
  }
  for (int k = q + 1 + lane; k < 204; k += 64) sArow[wave][k] = 0.f;
  int half = lane >> 5, li = lane & 31;
  const uint* Vu = (const uint*)V16 + rl(b * Lc * (Hc / 2) + h * (HSc / 2)) + li;
  float acc0 = 0.f, acc1 = 0.f, acc2 = 0.f, acc3 = 0.f;
  for (int k0 = 0; k0 <= q; k0 += 4) {
    int ka = k0 + half;
    int kb = k0 + 2 + half;
    int kca = (ka <= q) ? ka : q;
    int kcb = (kb <= q) ? kb : q;
    float aa = sArow[wave][ka];
    float ab = sArow[wave][kb];
    int ti0 = tmr[kca], di0 = dmr[kca];
    int ti1 = tmr[kcb], di1 = dmr[kcb];
    uint tv0 = tVs[ti0 * TROW + li];
    uint dv0 = dVs[di0 * TROW + li];
    uint vv0 = Vu[kca * (Hc / 2)];
    uint tv1 = tVs[ti1 * TROW + li];
    uint dv1 = dVs[di1 * TROW + li];
    uint vv1 = Vu[kcb * (Hc / 2)];
    h2 s0 = u2h(tv0) + u2h(dv0) + u2h(vv0);
    h2 s1 = u2h(tv1) + u2h(dv1) + u2h(vv1);
    acc0 = fmaf(aa, (float)s0.x, acc0);
    acc1 = fmaf(aa, (float)s0.y, acc1);
    acc2 = fmaf(ab, (float)s1.x, acc2);
    acc3 = fmaf(ab, (float)s1.y, acc3);
  }
  float accLo = acc0 + acc2; accLo += __shfl_xor(accLo, 32);
  float accHi = acc1 + acc3; accHi += __shfl_xor(accHi, 32);
  if (half == 0) {
    int oib = m * Hc + h * HSc + 2 * li;
    float2 qv = *(const float2*)&Qn[oib];
    float2 r;
    r.x = qv.x + accLo;
    r.y = qv.y + accHi;
    *(float2*)&seqs[oib] = r;
  }
}

// ---------------- fused LN2 + FFN1(relu) + FFN2 + residual + keep [+ lnf] ---
template <int FIN>
__global__ __launch_bounds__(512)
void ffn_k(float* __restrict__ seqs,
           const float* __restrict__ g, const float* __restrict__ bt,
           const ushort* __restrict__ W1_16, const float* __restrict__ b1,
           const ushort* __restrict__ W2_16, const float* __restrict__ b2,
           const int* __restrict__ logs,
           const float* __restrict__ lnf_g, const float* __restrict__ lnf_b,
           float* __restrict__ dout) {
  __shared__ __fp16 Xl[16][LDH];
  __shared__ __fp16 Hl[16][LDH];
  __shared__ __fp16 Wl[128][LDH];
  __shared__ float Ol[16][Hc];
  int m0 = blockIdx.x * 16;
  int t = threadIdx.x;
  {
    int r = t >> 5, c0 = (t & 31) * 8;
    const float* xr = &seqs[(m0 + r) * Hc + c0];
    float4 v0 = *(const float4*)&xr[0];
    float4 v1 = *(const float4*)&xr[4];
    float s = v0.x + v0.y + v0.z + v0.w + v1.x + v1.y + v1.z + v1.w;
    float q = v0.x*v0.x + v0.y*v0.y + v0.z*v0.z + v0.w*v0.w
            + v1.x*v1.x + v1.y*v1.y + v1.z*v1.z + v1.w*v1.w;
#pragma unroll
    for (int o = 1; o < 32; o <<= 1) { s += __shfl_xor(s, o); q += __shfl_xor(q, o); }
    float mean = s * (1.f / Hc);
    float var = q * (1.f / Hc) - mean * mean;
    float rstd = 1.f / sqrtf(var + 1e-8f);
    float tmp[8] = {v0.x,v0.y,v0.z,v0.w,v1.x,v1.y,v1.z,v1.w};
    float nv[8];
#pragma unroll
    for (int j = 0; j < 8; ++j)
      nv[j] = (tmp[j] - mean) * rstd * g[c0 + j] + bt[c0 + j];
#pragma unroll
    for (int j = 0; j < 8; j += 2)
      *(h2*)&Xl[r][c0 + j] = __builtin_amdgcn_cvt_pkrtz(nv[j], nv[j + 1]);
  }
  int wave = t >> 6, lane = t & 63;
  int row = lane & 15, kg = lane >> 4;
#pragma unroll
  for (int ch = 0; ch < 2; ++ch) {
    __syncthreads();
    for (int i = t; i < 4096; i += 512) {
      int r = i >> 5, c = (i & 31) * 8;
      uint4 v = *(const uint4*)&W1_16[(ch * 128 + r) * Hc + c];
      *(uint4*)&Wl[r][c] = v;
    }
    __syncthreads();
    int bn = wave * 16 + row;
    f32x4 acc = {0.f, 0.f, 0.f, 0.f};
#pragma unroll
    for (int k0 = 0; k0 < Hc; k0 += 32) {
      int kk = k0 + kg * 8;
      f16x8 a = *(const f16x8*)&Xl[row][kk];
      f16x8 bb = *(const f16x8*)&Wl[bn][kk];
      acc = __builtin_amdgcn_mfma_f32_16x16x32_f16(a, bb, acc, 0, 0, 0);
    }
    int coln = ch * 128 + wave * 16 + row;
    float bv = b1[coln];
#pragma unroll
    for (int r = 0; r < 4; ++r) {
      float v = fmaxf(acc[r] + bv, 0.f);
      Hl[kg * 4 + r][coln] = (_Float16)v;
    }
  }
#pragma unroll
  for (int ch = 0; ch < 2; ++ch) {
    __syncthreads();
    for (int i = t; i < 4096; i += 512) {
      int r = i >> 5, c = (i & 31) * 8;
      uint4 v = *(const uint4*)&W2_16[(ch * 128 + r) * Hc + c];
      *(uint4*)&Wl[r][c] = v;
    }
    __syncthreads();
    int bn = wave * 16 + row;
    f32x4 acc = {0.f, 0.f, 0.f, 0.f};
#pragma unroll
    for (int k0 = 0; k0 < Hc; k0 += 32) {
      int kk = k0 + kg * 8;
      f16x8 a = *(const f16x8*)&Hl[row][kk];
      f16x8 bb = *(const f16x8*)&Wl[bn][kk];
      acc = __builtin_amdgcn_mfma_f32_16x16x32_f16(a, bb, acc, 0, 0, 0);
    }
    int coln = ch * 128 + wave * 16 + row;
    float bv = b2[coln];
#pragma unroll
    for (int r = 0; r < 4; ++r) {
      int mrow = kg * 4 + r;
      int m = m0 + mrow;
      float keep = (logs[m] != 0) ? 1.f : 0.f;
      float xv = h2f(__builtin_bit_cast(ushort, Xl[mrow][coln]));
      float val = (acc[r] + bv + xv) * keep;
      if (FIN) Ol[mrow][coln] = val;
      else     seqs[m * Hc + coln] = val;
    }
  }
  if (FIN) {
    __syncthreads();
    int r = t >> 5, c0 = (t & 31) * 8;
    float v[8];
#pragma unroll
    for (int j = 0; j < 8; ++j) v[j] = Ol[r][c0 + j];
    float s = 0.f, q = 0.f;
#pragma unroll
    for (int j = 0; j < 8; ++j) { s += v[j]; q += v[j] * v[j]; }
#pragma unroll
    for (int o = 1; o < 32; o <<= 1) { s += __shfl_xor(s, o); q += __shfl_xor(q, o); }
    float mean = s * (1.f / Hc);
    float var = q * (1.f / Hc) - mean * mean;
    float rstd = 1.f / sqrtf(var + 1e-8f);
#pragma unroll
    for (int j = 0; j < 8; ++j)
      dout[(m0 + r) * Hc + c0 + j] = (v[j] - mean) * rstd * lnf_g[c0 + j] + lnf_b[c0 + j];
  }
}

extern "C" void kernel_launch(void* const* d_in, const int* in_sizes, int n_in,
                              void* d_out, int out_size, void* d_ws, size_t ws_size,
                              hipStream_t stream) {
  const int* logs = (const int*)d_in[0];
  const int* tm   = (const int*)d_in[1];
  const int* dm   = (const int*)d_in[2];
  const float* item = (const float*)d_in[3];
  const float* pK = (const float*)d_in[4];
  const float* pV = (const float*)d_in[5];
  const float* tK = (const float*)d_in[6];
  const float* tV = (const float*)d_in[7];
  const float* dK = (const float*)d_in[8];
  const float* dV = (const float*)d_in[9];
  const float* ln1_g = (const float*)d_in[10];
  const float* ln1_b = (const float*)d_in[11];
  const float* Wq = (const float*)d_in[12];
  const float* bq = (const float*)d_in[13];
  const float* Wk = (const float*)d_in[14];
  const float* bk = (const float*)d_in[15];
  const float* Wv = (const float*)d_in[16];
  const float* bv = (const float*)d_in[17];
  const float* ln2_g = (const float*)d_in[18];
  const float* ln2_b = (const float*)d_in[19];
  const float* W1 = (const float*)d_in[20];
  const float* b1 = (const float*)d_in[21];
  const float* W2 = (const float*)d_in[22];
  const float* b2 = (const float*)d_in[23];
  const float* lnf_g = (const float*)d_in[24];
  const float* lnf_b = (const float*)d_in[25];

  const int NROW = Mtot * Hc;          // 204800 floats
  float* ws = (float*)d_ws;
  float* sSeqs = ws + 0 * NROW;
  float* sQn   = ws + 1 * NROW;
  ushort* Q16  = (ushort*)(ws + 2 * NROW);
  ushort* K16  = Q16 + NROW;
  ushort* V16  = K16 + NROW;
  ushort* w16  = (ushort*)(ws + 4 * NROW);   // 5*WN + 4*TN halves
  ushort* wq16 = w16 + 0 * WN;
  ushort* wk16 = w16 + 1 * WN;
  ushort* wv16 = w16 + 2 * WN;
  ushort* w116 = w16 + 3 * WN;
  ushort* w216 = w16 + 4 * WN;
  ushort* tK16 = w16 + 5 * WN;
  ushort* tV16 = tK16 + TN;
  ushort* dK16 = tV16 + TN;
  ushort* dV16 = dK16 + TN;

  dim3 gC(64, 9);
  cvtw_k<<<gC, 256, 0, stream>>>(Wq, Wk, Wv, W1, W2, tK, tV, dK, dV, w16);

  dim3 gQKV(Mtot / 32, 12);
  dim3 ga(NHc, Bc, 16);
  const int HHh = Hc * Hc;
  for (int i = 0; i < NBc; ++i) {
    mmqkv_k<<<gQKV, 256, 0, stream>>>(sSeqs, item, logs, (i == 0) ? 1 : 0,
                                      ln1_g + i * Hc, ln1_b + i * Hc,
                                      wq16 + i * HHh, wk16 + i * HHh, wv16 + i * HHh,
                                      bq + i * Hc, bk + i * Hc, bv + i * Hc,
                                      pK, pV, sQn, Q16, K16, V16);
    attn_k<<<ga, 1024, 0, stream>>>(Q16, K16, V16,
                                    tK16, dK16, tV16, dV16,
                                    tm, dm, logs, sQn, sSeqs);
    if (i == 0)
      ffn_k<0><<<Mtot / 16, 512, 0, stream>>>(sSeqs, ln2_g + i * Hc, ln2_b + i * Hc,
                                              w116 + i * HHh, b1 + i * Hc,
                                              w216 + i * HHh, b2 + i * Hc, logs,
                                              nullptr, nullptr, nullptr);
    else
      ffn_k<1><<<Mtot / 16, 512, 0, stream>>>(sSeqs, ln2_g + i * Hc, ln2_b + i * Hc,
                                              w116 + i * HHh, b1 + i * Hc,
                                              w216 + i * HHh, b2 + i * Hc, logs,
                                              lnf_g, lnf_b, (float*)d_out);
  }
}

// Round 16
// 76.616 us; speedup vs baseline: 1.0969x; 1.0524x over previous
//
#include <hip/hip_runtime.h>
#include <math.h>

typedef __fp16 h2 __attribute__((ext_vector_type(2)));
typedef __fp16 f16x8 __attribute__((ext_vector_type(8)));
typedef float f32x4 __attribute__((ext_vector_type(4)));

#define Bc 4
#define Lc 200
#define Hc 256
#define NHc 4
#define HSc 64
#define NBc 2
#define Mtot (Bc*Lc)   // 800
#define TROW 34        // LDS table row stride in u32 (68 halfs = 136B)
#define LDH 264        // mm LDS row stride in halves (528B)
#define WN (2*Hc*Hc)   // 131072 halves per weight array (both layers)
#define TN (257*Hc)    // 65792 halves per table

static __device__ __forceinline__ float neg_fill() { return -4294967295.0f; }
static __device__ __forceinline__ int rl(int x) { return __builtin_amdgcn_readfirstlane(x); }

static __device__ __forceinline__ uint pkh2(float a, float b) {
  h2 r = __builtin_amdgcn_cvt_pkrtz(a, b);
  return __builtin_bit_cast(uint, r);
}
static __device__ __forceinline__ h2 u2h(uint u) { return __builtin_bit_cast(h2, u); }
static __device__ __forceinline__ float h2f(ushort u) {
  return (float)__builtin_bit_cast(_Float16, u);
}

// ---------------- one-shot f32 -> f16 conversion of weights & tables --------
__global__ void cvtw_k(const float* __restrict__ Wq, const float* __restrict__ Wk,
                       const float* __restrict__ Wv, const float* __restrict__ W1,
                       const float* __restrict__ W2,
                       const float* __restrict__ tK, const float* __restrict__ tV,
                       const float* __restrict__ dK, const float* __restrict__ dV,
                       ushort* __restrict__ out) {
  int y = blockIdx.y;
  const float* src;
  int n, off;
  if (y < 5) {
    n = WN; off = y * WN;
    src = (y == 0) ? Wq : (y == 1) ? Wk : (y == 2) ? Wv : (y == 3) ? W1 : W2;
  } else {
    n = TN; off = 5 * WN + (y - 5) * TN;
    src = (y == 5) ? tK : (y == 6) ? tV : (y == 7) ? dK : dV;
  }
  int idx = (blockIdx.x * 256 + threadIdx.x) * 8;
  if (idx >= n) return;
  float4 a = *(const float4*)&src[idx];
  float4 b = *(const float4*)&src[idx + 4];
  uint4 o;
  o.x = pkh2(a.x, a.y); o.y = pkh2(a.z, a.w);
  o.z = pkh2(b.x, b.y); o.w = pkh2(b.z, b.w);
  *(uint4*)&out[off + idx] = o;
}

// ---------------- fused [embed+] LN1 + QKV projections (f16 weights) --------
__global__ __launch_bounds__(256)
void mmqkv_k(const float* __restrict__ seqs, const float* __restrict__ emb,
             const int* __restrict__ logs, int useEmb,
             const float* __restrict__ g, const float* __restrict__ bt,
             const ushort* __restrict__ Wq16, const ushort* __restrict__ Wk16,
             const ushort* __restrict__ Wv16,
             const float* __restrict__ bq, const float* __restrict__ bk,
             const float* __restrict__ bv,
             const float* __restrict__ pK, const float* __restrict__ pV,
             float* __restrict__ Qn,
             ushort* __restrict__ Q16, ushort* __restrict__ K16,
             ushort* __restrict__ V16) {
  __shared__ __fp16 Al[16][LDH];
  __shared__ __fp16 Wl[64][LDH];
  int m0 = blockIdx.x * 16;
  int y = blockIdx.y;
  int region = y >> 2, nloc = (y & 3) * 64;
  const ushort* Wsrc = (region == 0) ? Wq16 : (region == 1 ? Wk16 : Wv16);
  const float* bias = (region == 0) ? bq : (region == 1 ? bk : bv);
  int t = threadIdx.x;
  if (region == 0) {
    int r = t >> 4, c0 = (t & 15) * 16;
    int m = m0 + r;
    const float* xr;
    bool zero = false;
    if (useEmb) {
      int tok = logs[m];
      zero = (tok == 0);
      xr = &emb[tok * Hc + c0];
    } else {
      xr = &seqs[m * Hc + c0];
    }
    float4 v0, v1, v2, v3;
    if (zero) {
      v0 = v1 = v2 = v3 = make_float4(0.f, 0.f, 0.f, 0.f);
    } else {
      v0 = *(const float4*)&xr[0];
      v1 = *(const float4*)&xr[4];
      v2 = *(const float4*)&xr[8];
      v3 = *(const float4*)&xr[12];
    }
    float s = v0.x + v0.y + v0.z + v0.w + v1.x + v1.y + v1.z + v1.w
            + v2.x + v2.y + v2.z + v2.w + v3.x + v3.y + v3.z + v3.w;
    float q = v0.x*v0.x + v0.y*v0.y + v0.z*v0.z + v0.w*v0.w
            + v1.x*v1.x + v1.y*v1.y + v1.z*v1.z + v1.w*v1.w
            + v2.x*v2.x + v2.y*v2.y + v2.z*v2.z + v2.w*v2.w
            + v3.x*v3.x + v3.y*v3.y + v3.z*v3.z + v3.w*v3.w;
#pragma unroll
    for (int o = 1; o < 16; o <<= 1) { s += __shfl_xor(s, o); q += __shfl_xor(q, o); }
    float mean = s * (1.f / Hc);
    float var = q * (1.f / Hc) - mean * mean;
    float rstd = 1.f / sqrtf(var + 1e-8f);
    float tmp[16] = {v0.x,v0.y,v0.z,v0.w,v1.x,v1.y,v1.z,v1.w,
                     v2.x,v2.y,v2.z,v2.w,v3.x,v3.y,v3.z,v3.w};
    float nv[16];
#pragma unroll
    for (int j = 0; j < 16; ++j)
      nv[j] = (tmp[j] - mean) * rstd * g[c0 + j] + bt[c0 + j];
#pragma unroll
    for (int j = 0; j < 16; j += 2)
      *(h2*)&Al[r][c0 + j] = __builtin_amdgcn_cvt_pkrtz(nv[j], nv[j + 1]);
    if (y == 0) {
#pragma unroll
      for (int j = 0; j < 16; j += 4)
        *(float4*)&Qn[m * Hc + c0 + j] = make_float4(nv[j], nv[j+1], nv[j+2], nv[j+3]);
    }
  } else {
    for (int i = t; i < 16 * 64; i += 256) {
      int r = i >> 6, c = (i & 63) * 4;
      int m = m0 + r;
      float4 v;
      if (useEmb) {
        int tok = logs[m];
        v = (tok == 0) ? make_float4(0.f, 0.f, 0.f, 0.f)
                       : *(const float4*)&emb[tok * Hc + c];
      } else {
        v = *(const float4*)&seqs[m * Hc + c];
      }
      *(h2*)&Al[r][c] = __builtin_amdgcn_cvt_pkrtz(v.x, v.y);
      *(h2*)&Al[r][c + 2] = __builtin_amdgcn_cvt_pkrtz(v.z, v.w);
    }
  }
  for (int i = t; i < 2048; i += 256) {
    int r = i >> 5, c = (i & 31) * 8;
    uint4 v = *(const uint4*)&Wsrc[(nloc + r) * Hc + c];
    *(uint4*)&Wl[r][c] = v;
  }
  __syncthreads();
  int wave = t >> 6, lane = t & 63;
  int row = lane & 15, kg = lane >> 4;
  int bn = wave * 16 + row;
  f32x4 acc = {0.f, 0.f, 0.f, 0.f};
#pragma unroll
  for (int k0 = 0; k0 < Hc; k0 += 32) {
    int kk = k0 + kg * 8;
    f16x8 a = *(const f16x8*)&Al[row][kk];
    f16x8 bb = *(const f16x8*)&Wl[bn][kk];
    acc = __builtin_amdgcn_mfma_f32_16x16x32_f16(a, bb, acc, 0, 0, 0);
  }
  int coln = nloc + wave * 16 + row;
  ushort* op = (region == 0) ? Q16 : (region == 1 ? K16 : V16);
  const float* pT = (region == 1) ? pK : pV;
#pragma unroll
  for (int r = 0; r < 4; ++r) {
    int m = m0 + kg * 4 + r;
    float v = acc[r] + bias[coln];
    if (region) v += pT[(m % Lc) * Hc + coln];
    op[m * Hc + coln] = __builtin_bit_cast(ushort, (_Float16)v);
  }
}

// ---------------- fused attention: MFMA scores + softmax + paired-k out -----
// grid (NHc, Bc, 16) = 256 blocks; block 1024 (16 waves), wave w owns q=16w+bz.
__global__ __launch_bounds__(1024, 4)
void attn_k(const ushort* __restrict__ Q16, const ushort* __restrict__ K16,
            const ushort* __restrict__ V16,
            const ushort* __restrict__ tK16, const ushort* __restrict__ dK16,
            const ushort* __restrict__ tV16, const ushort* __restrict__ dV16,
            const int* __restrict__ tm, const int* __restrict__ dm,
            const int* __restrict__ logs,
            const float* __restrict__ Qn, float* __restrict__ seqs) {
  int h = blockIdx.x, b = blockIdx.y, bz = blockIdx.z;
  __shared__ uint tVs[257 * TROW];
  __shared__ uint dVs[257 * TROW];
  __shared__ float S0l[16][212];
  __shared__ float Tql[16][272];
  __shared__ float Dql[16][272];
  __shared__ float sArow[16][204];
  int t = threadIdx.x;
  int wave = t >> 6, lane = t & 63;
  int row16 = lane & 15, kg = lane >> 4;
  // ---- stage tV/dV (out-phase tables) ----
  {
    const ushort* s1 = tV16 + h * HSc;
    const ushort* s2 = dV16 + h * HSc;
    for (int i = t; i < 257 * 8; i += 1024) {
      int r = i >> 3, c = (i & 7) * 8;
      *(uint4*)&tVs[r * TROW + (c >> 1)] = *(const uint4*)&s1[r * Hc + c];
      *(uint4*)&dVs[r * TROW + (c >> 1)] = *(const uint4*)&s2[r * Hc + c];
    }
  }
  // ---- phase 1: MFMA tile-jobs ----
  {
    int qa = row16 * 16 + bz;               // A-row (strided q of this block)
    bool va = qa < Lc;
    f16x8 A0 = {0,0,0,0,0,0,0,0}, A1 = A0;
    if (va) {
      const ushort* Qr = &Q16[(b * Lc + qa) * Hc + h * HSc];
      A0 = *(const f16x8*)&Qr[kg * 8];
      A1 = *(const f16x8*)&Qr[32 + kg * 8];
    }
    for (int j = wave; j < 47; j += 16) {
      int kind, n;
      if (j < 13) { kind = 0; n = j; }
      else if (j < 30) { kind = 1; n = j - 13; }
      else { kind = 2; n = j - 30; }
      int col = n * 16 + row16;
      const ushort* Bsrc;
      bool vb;
      if (kind == 0) { vb = col < Lc; Bsrc = &K16[(b * Lc + (vb ? col : 0)) * Hc + h * HSc]; }
      else { vb = col < 257; Bsrc = &((kind == 1) ? tK16 : dK16)[(vb ? col : 0) * Hc + h * HSc]; }
      f16x8 B0 = {0,0,0,0,0,0,0,0}, B1 = B0;
      if (vb) {
        B0 = *(const f16x8*)&Bsrc[kg * 8];
        B1 = *(const f16x8*)&Bsrc[32 + kg * 8];
      }
      f32x4 acc = {0.f, 0.f, 0.f, 0.f};
      acc = __builtin_amdgcn_mfma_f32_16x16x32_f16(A0, B0, acc, 0, 0, 0);
      acc = __builtin_amdgcn_mfma_f32_16x16x32_f16(A1, B1, acc, 0, 0, 0);
      if (kind == 0) {
#pragma unroll
        for (int r = 0; r < 4; ++r) S0l[kg * 4 + r][col] = acc[r];
      } else if (kind == 1) {
#pragma unroll
        for (int r = 0; r < 4; ++r) Tql[kg * 4 + r][col] = acc[r];
      } else {
#pragma unroll
        for (int r = 0; r < 4; ++r) Dql[kg * 4 + r][col] = acc[r];
      }
    }
  }
  __syncthreads();
  // ---- phase 2: per-wave score assembly + softmax + output ----
  int q = wave * 16 + bz;
  if (q >= Lc) return;
  int m = b * Lc + q;
  int oi = m * Hc + h * HSc + lane;
  if (logs[m] == 0) { seqs[oi] = Qn[oi]; return; }
  const int* tmr = tm + rl(m * Lc);
  const int* dmr = dm + rl(m * Lc);
  const float* srow = S0l[wave];
  const float* trow = Tql[wave];
  const float* drow = Dql[wave];
  int np = (q >> 6) + 1;
  float sv[4];
  float mx = neg_fill();
#pragma unroll
  for (int p = 0; p < 4; ++p) {
    sv[p] = neg_fill();
    if (p >= np) continue;
    int k = p * 64 + lane;
    int kc = (k <= q) ? k : q;
    int ti = tmr[kc], di = dmr[kc];
    float sc = (srow[kc] + trow[ti] + drow[di]) * 0.125f;
    if (k <= q) sv[p] = sc;
    mx = fmaxf(mx, sv[p]);
  }
#pragma unroll
  for (int o = 32; o; o >>= 1) mx = fmaxf(mx, __shfl_xor(mx, o));
  float sum = 0.f;
  float ev[4];
#pragma unroll
  for (int p = 0; p < 4; ++p) {
    ev[p] = __expf(sv[p] - mx);
    sum += ev[p];
  }
#pragma unroll
  for (int o = 32; o; o >>= 1) sum += __shfl_xor(sum, o);
  float rs = 1.f / sum;
#pragma unroll
  for (int p = 0; p < 4; ++p) {
    if (p >= np) continue;
    int k = p * 64 + lane;
    if (k < Lc) sArow[wave][k] = ev[p] * rs;
  }
  for (int k = q + 1 + lane; k < 204; k += 64) sArow[wave][k] = 0.f;
  int half = lane >> 5, li = lane & 31;
  const uint* Vu = (const uint*)V16 + rl(b * Lc * (Hc / 2) + h * (HSc / 2)) + li;
  float acc0 = 0.f, acc1 = 0.f, acc2 = 0.f, acc3 = 0.f;
  for (int k0 = 0; k0 <= q; k0 += 4) {
    int ka = k0 + half;
    int kb = k0 + 2 + half;
    int kca = (ka <= q) ? ka : q;
    int kcb = (kb <= q) ? kb : q;
    float aa = sArow[wave][ka];
    float ab = sArow[wave][kb];
    int ti0 = tmr[kca], di0 = dmr[kca];
    int ti1 = tmr[kcb], di1 = dmr[kcb];
    uint tv0 = tVs[ti0 * TROW + li];
    uint dv0 = dVs[di0 * TROW + li];
    uint vv0 = Vu[kca * (Hc / 2)];
    uint tv1 = tVs[ti1 * TROW + li];
    uint dv1 = dVs[di1 * TROW + li];
    uint vv1 = Vu[kcb * (Hc / 2)];
    h2 s0 = u2h(tv0) + u2h(dv0) + u2h(vv0);
    h2 s1 = u2h(tv1) + u2h(dv1) + u2h(vv1);
    acc0 = fmaf(aa, (float)s0.x, acc0);
    acc1 = fmaf(aa, (float)s0.y, acc1);
    acc2 = fmaf(ab, (float)s1.x, acc2);
    acc3 = fmaf(ab, (float)s1.y, acc3);
  }
  float accLo = acc0 + acc2; accLo += __shfl_xor(accLo, 32);
  float accHi = acc1 + acc3; accHi += __shfl_xor(accHi, 32);
  if (half == 0) {
    int oib = m * Hc + h * HSc + 2 * li;
    float2 qv = *(const float2*)&Qn[oib];
    float2 r;
    r.x = qv.x + accLo;
    r.y = qv.y + accHi;
    *(float2*)&seqs[oib] = r;
  }
}

// ---------------- fused LN2 + FFN1(relu) + FFN2 + residual + keep [+ lnf] ---
template <int FIN>
__global__ __launch_bounds__(512)
void ffn_k(float* __restrict__ seqs,
           const float* __restrict__ g, const float* __restrict__ bt,
           const ushort* __restrict__ W1_16, const float* __restrict__ b1,
           const ushort* __restrict__ W2_16, const float* __restrict__ b2,
           const int* __restrict__ logs,
           const float* __restrict__ lnf_g, const float* __restrict__ lnf_b,
           float* __restrict__ dout) {
  __shared__ __fp16 Xl[16][LDH];
  __shared__ __fp16 Hl[16][LDH];
  __shared__ __fp16 Wl[128][LDH];
  __shared__ float Ol[16][Hc];
  int m0 = blockIdx.x * 16;
  int t = threadIdx.x;
  {
    int r = t >> 5, c0 = (t & 31) * 8;
    const float* xr = &seqs[(m0 + r) * Hc + c0];
    float4 v0 = *(const float4*)&xr[0];
    float4 v1 = *(const float4*)&xr[4];
    float s = v0.x + v0.y + v0.z + v0.w + v1.x + v1.y + v1.z + v1.w;
    float q = v0.x*v0.x + v0.y*v0.y + v0.z*v0.z + v0.w*v0.w
            + v1.x*v1.x + v1.y*v1.y + v1.z*v1.z + v1.w*v1.w;
#pragma unroll
    for (int o = 1; o < 32; o <<= 1) { s += __shfl_xor(s, o); q += __shfl_xor(q, o); }
    float mean = s * (1.f / Hc);
    float var = q * (1.f / Hc) - mean * mean;
    float rstd = 1.f / sqrtf(var + 1e-8f);
    float tmp[8] = {v0.x,v0.y,v0.z,v0.w,v1.x,v1.y,v1.z,v1.w};
    float nv[8];
#pragma unroll
    for (int j = 0; j < 8; ++j)
      nv[j] = (tmp[j] - mean) * rstd * g[c0 + j] + bt[c0 + j];
#pragma unroll
    for (int j = 0; j < 8; j += 2)
      *(h2*)&Xl[r][c0 + j] = __builtin_amdgcn_cvt_pkrtz(nv[j], nv[j + 1]);
  }
  int wave = t >> 6, lane = t & 63;
  int row = lane & 15, kg = lane >> 4;
#pragma unroll
  for (int ch = 0; ch < 2; ++ch) {
    __syncthreads();
    for (int i = t; i < 4096; i += 512) {
      int r = i >> 5, c = (i & 31) * 8;
      uint4 v = *(const uint4*)&W1_16[(ch * 128 + r) * Hc + c];
      *(uint4*)&Wl[r][c] = v;
    }
    __syncthreads();
    int bn = wave * 16 + row;
    f32x4 acc = {0.f, 0.f, 0.f, 0.f};
#pragma unroll
    for (int k0 = 0; k0 < Hc; k0 += 32) {
      int kk = k0 + kg * 8;
      f16x8 a = *(const f16x8*)&Xl[row][kk];
      f16x8 bb = *(const f16x8*)&Wl[bn][kk];
      acc = __builtin_amdgcn_mfma_f32_16x16x32_f16(a, bb, acc, 0, 0, 0);
    }
    int coln = ch * 128 + wave * 16 + row;
    float bv = b1[coln];
#pragma unroll
    for (int r = 0; r < 4; ++r) {
      float v = fmaxf(acc[r] + bv, 0.f);
      Hl[kg * 4 + r][coln] = (_Float16)v;
    }
  }
#pragma unroll
  for (int ch = 0; ch < 2; ++ch) {
    __syncthreads();
    for (int i = t; i < 4096; i += 512) {
      int r = i >> 5, c = (i & 31) * 8;
      uint4 v = *(const uint4*)&W2_16[(ch * 128 + r) * Hc + c];
      *(uint4*)&Wl[r][c] = v;
    }
    __syncthreads();
    int bn = wave * 16 + row;
    f32x4 acc = {0.f, 0.f, 0.f, 0.f};
#pragma unroll
    for (int k0 = 0; k0 < Hc; k0 += 32) {
      int kk = k0 + kg * 8;
      f16x8 a = *(const f16x8*)&Hl[row][kk];
      f16x8 bb = *(const f16x8*)&Wl[bn][kk];
      acc = __builtin_amdgcn_mfma_f32_16x16x32_f16(a, bb, acc, 0, 0, 0);
    }
    int coln = ch * 128 + wave * 16 + row;
    float bv = b2[coln];
#pragma unroll
    for (int r = 0; r < 4; ++r) {
      int mrow = kg * 4 + r;
      int m = m0 + mrow;
      float keep = (logs[m] != 0) ? 1.f : 0.f;
      float xv = h2f(__builtin_bit_cast(ushort, Xl[mrow][coln]));
      float val = (acc[r] + bv + xv) * keep;
      if (FIN) Ol[mrow][coln] = val;
      else     seqs[m * Hc + coln] = val;
    }
  }
  if (FIN) {
    __syncthreads();
    int r = t >> 5, c0 = (t & 31) * 8;
    float v[8];
#pragma unroll
    for (int j = 0; j < 8; ++j) v[j] = Ol[r][c0 + j];
    float s = 0.f, q = 0.f;
#pragma unroll
    for (int j = 0; j < 8; ++j) { s += v[j]; q += v[j] * v[j]; }
#pragma unroll
    for (int o = 1; o < 32; o <<= 1) { s += __shfl_xor(s, o); q += __shfl_xor(q, o); }
    float mean = s * (1.f / Hc);
    float var = q * (1.f / Hc) - mean * mean;
    float rstd = 1.f / sqrtf(var + 1e-8f);
#pragma unroll
    for (int j = 0; j < 8; ++j)
      dout[(m0 + r) * Hc + c0 + j] = (v[j] - mean) * rstd * lnf_g[c0 + j] + lnf_b[c0 + j];
  }
}

extern "C" void kernel_launch(void* const* d_in, const int* in_sizes, int n_in,
                              void* d_out, int out_size, void* d_ws, size_t ws_size,
                              hipStream_t stream) {
  const int* logs = (const int*)d_in[0];
  const int* tm   = (const int*)d_in[1];
  const int* dm   = (const int*)d_in[2];
  const float* item = (const float*)d_in[3];
  const float* pK = (const float*)d_in[4];
  const float* pV = (const float*)d_in[5];
  const float* tK = (const float*)d_in[6];
  const float* tV = (const float*)d_in[7];
  const float* dK = (const float*)d_in[8];
  const float* dV = (const float*)d_in[9];
  const float* ln1_g = (const float*)d_in[10];
  const float* ln1_b = (const float*)d_in[11];
  const float* Wq = (const float*)d_in[12];
  const float* bq = (const float*)d_in[13];
  const float* Wk = (const float*)d_in[14];
  const float* bk = (const float*)d_in[15];
  const float* Wv = (const float*)d_in[16];
  const float* bv = (const float*)d_in[17];
  const float* ln2_g = (const float*)d_in[18];
  const float* ln2_b = (const float*)d_in[19];
  const float* W1 = (const float*)d_in[20];
  const float* b1 = (const float*)d_in[21];
  const float* W2 = (const float*)d_in[22];
  const float* b2 = (const float*)d_in[23];
  const float* lnf_g = (const float*)d_in[24];
  const float* lnf_b = (const float*)d_in[25];

  const int NROW = Mtot * Hc;          // 204800 floats
  float* ws = (float*)d_ws;
  float* sSeqs = ws + 0 * NROW;
  float* sQn   = ws + 1 * NROW;
  ushort* Q16  = (ushort*)(ws + 2 * NROW);
  ushort* K16  = Q16 + NROW;
  ushort* V16  = K16 + NROW;
  ushort* w16  = (ushort*)(ws + 4 * NROW);   // 5*WN + 4*TN halves
  ushort* wq16 = w16 + 0 * WN;
  ushort* wk16 = w16 + 1 * WN;
  ushort* wv16 = w16 + 2 * WN;
  ushort* w116 = w16 + 3 * WN;
  ushort* w216 = w16 + 4 * WN;
  ushort* tK16 = w16 + 5 * WN;
  ushort* tV16 = tK16 + TN;
  ushort* dK16 = tV16 + TN;
  ushort* dV16 = dK16 + TN;

  dim3 gC(64, 9);
  cvtw_k<<<gC, 256, 0, stream>>>(Wq, Wk, Wv, W1, W2, tK, tV, dK, dV, w16);

  dim3 gQKV(Mtot / 16, 12);
  dim3 ga(NHc, Bc, 16);
  const int HHh = Hc * Hc;
  for (int i = 0; i < NBc; ++i) {
    mmqkv_k<<<gQKV, 256, 0, stream>>>(sSeqs, item, logs, (i == 0) ? 1 : 0,
                                      ln1_g + i * Hc, ln1_b + i * Hc,
                                      wq16 + i * HHh, wk16 + i * HHh, wv16 + i * HHh,
                                      bq + i * Hc, bk + i * Hc, bv + i * Hc,
                                      pK, pV, sQn, Q16, K16, V16);
    attn_k<<<ga, 1024, 0, stream>>>(Q16, K16, V16,
                                    tK16, dK16, tV16, dV16,
                                    tm, dm, logs, sQn, sSeqs);
    if (i == 0)
      ffn_k<0><<<Mtot / 16, 512, 0, stream>>>(sSeqs, ln2_g + i * Hc, ln2_b + i * Hc,
                                              w116 + i * HHh, b1 + i * Hc,
                                              w216 + i * HHh, b2 + i * Hc, logs,
                                              nullptr, nullptr, nullptr);
    else
      ffn_k<1><<<Mtot / 16, 512, 0, stream>>>(sSeqs, ln2_g + i * Hc, ln2_b + i * Hc,
                                              w116 + i * HHh, b1 + i * Hc,
                                              w216 + i * HHh, b2 + i * Hc, logs,
                                              lnf_g, lnf_b, (float*)d_out);
  }
}

// Round 17
// 69.020 us; speedup vs baseline: 1.2176x; 1.1101x over previous
//
#include <hip/hip_runtime.h>
#include <math.h>

typedef __fp16 h2 __attribute__((ext_vector_type(2)));
typedef __fp16 f16x8 __attribute__((ext_vector_type(8)));
typedef float f32x4 __attribute__((ext_vector_type(4)));

#define Bc 4
#define Lc 200
#define Hc 256
#define NHc 4
#define HSc 64
#define NBc 2
#define Mtot (Bc*Lc)   // 800
#define LDH 264        // mm LDS row stride in halves (528B)
#define WN (2*Hc*Hc)   // 131072 halves per weight array (both layers)
#define TN (257*Hc)    // 65792 halves per table
#define TTW 288        // transposed-table row width (halves), zero-padded past 257
#define VTW 224        // transposed-V row width (halves), cols >=200 garbage (A zero-masked)

static __device__ __forceinline__ float neg_fill() { return -4294967295.0f; }
static __device__ __forceinline__ int rl(int x) { return __builtin_amdgcn_readfirstlane(x); }

static __device__ __forceinline__ uint pkh2(float a, float b) {
  h2 r = __builtin_amdgcn_cvt_pkrtz(a, b);
  return __builtin_bit_cast(uint, r);
}
static __device__ __forceinline__ h2 u2h(uint u) { return __builtin_bit_cast(h2, u); }
static __device__ __forceinline__ float h2f(ushort u) {
  return (float)__builtin_bit_cast(_Float16, u);
}

// ---------------- one-shot f32 -> f16 conversion of weights & tables --------
// y 0..4: weights; y 5..8: row-major tables; y 9..10: transposed tV/dV (padded)
__global__ void cvtw_k(const float* __restrict__ Wq, const float* __restrict__ Wk,
                       const float* __restrict__ Wv, const float* __restrict__ W1,
                       const float* __restrict__ W2,
                       const float* __restrict__ tK, const float* __restrict__ tV,
                       const float* __restrict__ dK, const float* __restrict__ dV,
                       ushort* __restrict__ out) {
  int y = blockIdx.y;
  if (y >= 9) {
    const float* srcT = (y == 9) ? tV : dV;
    ushort* dst = out + 5 * WN + 4 * TN + (y - 9) * (Hc * TTW);
    int idx = (blockIdx.x * 256 + threadIdx.x) * 8;
    if (idx >= Hc * TTW) return;
    int hd = idx / TTW, c0 = idx % TTW;     // c0 multiple of 8
    ushort v[8];
#pragma unroll
    for (int j = 0; j < 8; ++j) {
      int c = c0 + j;
      float f = (c < 257) ? srcT[c * Hc + hd] : 0.f;
      v[j] = __builtin_bit_cast(ushort, (_Float16)f);
    }
    *(uint4*)&dst[idx] = *(uint4*)v;
    return;
  }
  const float* src;
  int n, off;
  if (y < 5) {
    n = WN; off = y * WN;
    src = (y == 0) ? Wq : (y == 1) ? Wk : (y == 2) ? Wv : (y == 3) ? W1 : W2;
  } else {
    n = TN; off = 5 * WN + (y - 5) * TN;
    src = (y == 5) ? tK : (y == 6) ? tV : (y == 7) ? dK : dV;
  }
  int idx = (blockIdx.x * 256 + threadIdx.x) * 8;
  if (idx >= n) return;
  float4 a = *(const float4*)&src[idx];
  float4 b = *(const float4*)&src[idx + 4];
  uint4 o;
  o.x = pkh2(a.x, a.y); o.y = pkh2(a.z, a.w);
  o.z = pkh2(b.x, b.y); o.w = pkh2(b.z, b.w);
  *(uint4*)&out[off + idx] = o;
}

// ---------------- fused [embed+] LN1 + QKV projections (f16 weights) --------
// Q/K written row-major f16; V written TRANSPOSED (Vt[b][hd][q], width VTW).
__global__ __launch_bounds__(256)
void mmqkv_k(const float* __restrict__ seqs, const float* __restrict__ emb,
             const int* __restrict__ logs, int useEmb,
             const float* __restrict__ g, const float* __restrict__ bt,
             const ushort* __restrict__ Wq16, const ushort* __restrict__ Wk16,
             const ushort* __restrict__ Wv16,
             const float* __restrict__ bq, const float* __restrict__ bk,
             const float* __restrict__ bv,
             const float* __restrict__ pK, const float* __restrict__ pV,
             float* __restrict__ Qn,
             ushort* __restrict__ Q16, ushort* __restrict__ K16,
             ushort* __restrict__ Vt) {
  __shared__ __fp16 Al[16][LDH];
  __shared__ __fp16 Wl[64][LDH];
  int m0 = blockIdx.x * 16;
  int y = blockIdx.y;
  int region = y >> 2, nloc = (y & 3) * 64;
  const ushort* Wsrc = (region == 0) ? Wq16 : (region == 1 ? Wk16 : Wv16);
  const float* bias = (region == 0) ? bq : (region == 1 ? bk : bv);
  int t = threadIdx.x;
  if (region == 0) {
    int r = t >> 4, c0 = (t & 15) * 16;
    int m = m0 + r;
    const float* xr;
    bool zero = false;
    if (useEmb) {
      int tok = logs[m];
      zero = (tok == 0);
      xr = &emb[tok * Hc + c0];
    } else {
      xr = &seqs[m * Hc + c0];
    }
    float4 v0, v1, v2, v3;
    if (zero) {
      v0 = v1 = v2 = v3 = make_float4(0.f, 0.f, 0.f, 0.f);
    } else {
      v0 = *(const float4*)&xr[0];
      v1 = *(const float4*)&xr[4];
      v2 = *(const float4*)&xr[8];
      v3 = *(const float4*)&xr[12];
    }
    float s = v0.x + v0.y + v0.z + v0.w + v1.x + v1.y + v1.z + v1.w
            + v2.x + v2.y + v2.z + v2.w + v3.x + v3.y + v3.z + v3.w;
    float q = v0.x*v0.x + v0.y*v0.y + v0.z*v0.z + v0.w*v0.w
            + v1.x*v1.x + v1.y*v1.y + v1.z*v1.z + v1.w*v1.w
            + v2.x*v2.x + v2.y*v2.y + v2.z*v2.z + v2.w*v2.w
            + v3.x*v3.x + v3.y*v3.y + v3.z*v3.z + v3.w*v3.w;
#pragma unroll
    for (int o = 1; o < 16; o <<= 1) { s += __shfl_xor(s, o); q += __shfl_xor(q, o); }
    float mean = s * (1.f / Hc);
    float var = q * (1.f / Hc) - mean * mean;
    float rstd = 1.f / sqrtf(var + 1e-8f);
    float tmp[16] = {v0.x,v0.y,v0.z,v0.w,v1.x,v1.y,v1.z,v1.w,
                     v2.x,v2.y,v2.z,v2.w,v3.x,v3.y,v3.z,v3.w};
    float nv[16];
#pragma unroll
    for (int j = 0; j < 16; ++j)
      nv[j] = (tmp[j] - mean) * rstd * g[c0 + j] + bt[c0 + j];
#pragma unroll
    for (int j = 0; j < 16; j += 2)
      *(h2*)&Al[r][c0 + j] = __builtin_amdgcn_cvt_pkrtz(nv[j], nv[j + 1]);
    if (y == 0) {
#pragma unroll
      for (int j = 0; j < 16; j += 4)
        *(float4*)&Qn[m * Hc + c0 + j] = make_float4(nv[j], nv[j+1], nv[j+2], nv[j+3]);
    }
  } else {
    for (int i = t; i < 16 * 64; i += 256) {
      int r = i >> 6, c = (i & 63) * 4;
      int m = m0 + r;
      float4 v;
      if (useEmb) {
        int tok = logs[m];
        v = (tok == 0) ? make_float4(0.f, 0.f, 0.f, 0.f)
                       : *(const float4*)&emb[tok * Hc + c];
      } else {
        v = *(const float4*)&seqs[m * Hc + c];
      }
      *(h2*)&Al[r][c] = __builtin_amdgcn_cvt_pkrtz(v.x, v.y);
      *(h2*)&Al[r][c + 2] = __builtin_amdgcn_cvt_pkrtz(v.z, v.w);
    }
  }
  for (int i = t; i < 2048; i += 256) {
    int r = i >> 5, c = (i & 31) * 8;
    uint4 v = *(const uint4*)&Wsrc[(nloc + r) * Hc + c];
    *(uint4*)&Wl[r][c] = v;
  }
  __syncthreads();
  int wave = t >> 6, lane = t & 63;
  int row = lane & 15, kg = lane >> 4;
  int bn = wave * 16 + row;
  f32x4 acc = {0.f, 0.f, 0.f, 0.f};
#pragma unroll
  for (int k0 = 0; k0 < Hc; k0 += 32) {
    int kk = k0 + kg * 8;
    f16x8 a = *(const f16x8*)&Al[row][kk];
    f16x8 bb = *(const f16x8*)&Wl[bn][kk];
    acc = __builtin_amdgcn_mfma_f32_16x16x32_f16(a, bb, acc, 0, 0, 0);
  }
  int coln = nloc + wave * 16 + row;
  float bcol = bias[coln];
  if (region == 2) {
    // transposed store: Vt[b][coln][q0..q0+3] (4 consecutive halves, one uint2)
    int mbase = m0 + kg * 4;
    int b2 = mbase / Lc;
    int q0 = mbase - b2 * Lc;        // 4-aligned (200 % 4 == 0, m0 % 4 == 0)
    float v0 = acc[0] + bcol + pV[(q0 + 0) * Hc + coln];
    float v1 = acc[1] + bcol + pV[(q0 + 1) * Hc + coln];
    float v2 = acc[2] + bcol + pV[(q0 + 2) * Hc + coln];
    float v3 = acc[3] + bcol + pV[(q0 + 3) * Hc + coln];
    uint2 pk;
    pk.x = pkh2(v0, v1);
    pk.y = pkh2(v2, v3);
    *(uint2*)&Vt[((size_t)(b2 * Hc + coln)) * VTW + q0] = pk;
  } else {
    ushort* op = (region == 0) ? Q16 : K16;
#pragma unroll
    for (int r = 0; r < 4; ++r) {
      int m = m0 + kg * 4 + r;
      float v = acc[r] + bcol;
      if (region) v += pK[(m % Lc) * Hc + coln];
      op[m * Hc + coln] = __builtin_bit_cast(ushort, (_Float16)v);
    }
  }
}

// ---------------- fused attention: MFMA scores + softmax + histogram + MFMA PV
// grid (NHc, Bc, 16) = 256 blocks; block 1024 (16 waves), wave w owns q=16w+bz.
// Phase 1: S0/Tq/Dq via MFMA. Phase 2: softmax -> A16 (f16) + per-row histograms.
// Phase 3: 12 MFMA jobs: O = A16.V + Wt.tV + Wd.dV (transposed B operands).
__global__ __launch_bounds__(1024, 4)
void attn_k(const ushort* __restrict__ Q16, const ushort* __restrict__ K16,
            const ushort* __restrict__ Vt,
            const ushort* __restrict__ tK16, const ushort* __restrict__ dK16,
            const ushort* __restrict__ tVt, const ushort* __restrict__ dVt,
            const int* __restrict__ tm, const int* __restrict__ dm,
            const int* __restrict__ logs,
            const float* __restrict__ Qn, float* __restrict__ seqs) {
  int h = blockIdx.x, b = blockIdx.y, bz = blockIdx.z;
  __shared__ float S0l[16][212];
  __shared__ float Tql[16][272];
  __shared__ float Dql[16][272];
  __shared__ __fp16 A16[16][296];
  __shared__ float binsT[16][264];
  __shared__ float binsD[16][264];
  __shared__ __fp16 Wt16[16][296];
  __shared__ __fp16 Wd16[16][296];
  __shared__ float Opart[3][16][64];
  int t = threadIdx.x;
  int wave = t >> 6, lane = t & 63;
  int row16 = lane & 15, kg = lane >> 4;
  // zero histograms
  for (int i = t; i < 16 * 264; i += 1024) {
    (&binsT[0][0])[i] = 0.f;
    (&binsD[0][0])[i] = 0.f;
  }
  // ---- phase 1: MFMA tile-jobs (S0 = Q.K'^T, Tq = Q.tK^T, Dq = Q.dK^T) ----
  {
    int qa = row16 * 16 + bz;
    bool va = qa < Lc;
    f16x8 A0 = {0,0,0,0,0,0,0,0}, A1 = A0;
    if (va) {
      const ushort* Qr = &Q16[(b * Lc + qa) * Hc + h * HSc];
      A0 = *(const f16x8*)&Qr[kg * 8];
      A1 = *(const f16x8*)&Qr[32 + kg * 8];
    }
    for (int j = wave; j < 47; j += 16) {
      int kind, n;
      if (j < 13) { kind = 0; n = j; }
      else if (j < 30) { kind = 1; n = j - 13; }
      else { kind = 2; n = j - 30; }
      int col = n * 16 + row16;
      const ushort* Bsrc;
      bool vb;
      if (kind == 0) { vb = col < Lc; Bsrc = &K16[(b * Lc + (vb ? col : 0)) * Hc + h * HSc]; }
      else { vb = col < 257; Bsrc = &((kind == 1) ? tK16 : dK16)[(vb ? col : 0) * Hc + h * HSc]; }
      f16x8 B0 = {0,0,0,0,0,0,0,0}, B1 = B0;
      if (vb) {
        B0 = *(const f16x8*)&Bsrc[kg * 8];
        B1 = *(const f16x8*)&Bsrc[32 + kg * 8];
      }
      f32x4 acc = {0.f, 0.f, 0.f, 0.f};
      acc = __builtin_amdgcn_mfma_f32_16x16x32_f16(A0, B0, acc, 0, 0, 0);
      acc = __builtin_amdgcn_mfma_f32_16x16x32_f16(A1, B1, acc, 0, 0, 0);
      if (kind == 0) {
#pragma unroll
        for (int r = 0; r < 4; ++r) S0l[kg * 4 + r][col] = acc[r];
      } else if (kind == 1) {
#pragma unroll
        for (int r = 0; r < 4; ++r) Tql[kg * 4 + r][col] = acc[r];
      } else {
#pragma unroll
        for (int r = 0; r < 4; ++r) Dql[kg * 4 + r][col] = acc[r];
      }
    }
  }
  __syncthreads();
  // ---- phase 2: per-wave score assembly + softmax + A16/histogram ----
  int q = wave * 16 + bz;
  int m = b * Lc + q;
  bool valid = false;
  if (q < Lc) valid = (logs[m] != 0);
  if (valid) {
    const int* tmr = tm + rl(m * Lc);
    const int* dmr = dm + rl(m * Lc);
    const float* srow = S0l[wave];
    const float* trow = Tql[wave];
    const float* drow = Dql[wave];
    int np = (q >> 6) + 1;
    float sv[4];
    float mx = neg_fill();
#pragma unroll
    for (int p = 0; p < 4; ++p) {
      sv[p] = neg_fill();
      if (p >= np) continue;
      int k = p * 64 + lane;
      int kc = (k <= q) ? k : q;
      int ti = tmr[kc], di = dmr[kc];
      float sc = (srow[kc] + trow[ti] + drow[di]) * 0.125f;
      if (k <= q) sv[p] = sc;
      mx = fmaxf(mx, sv[p]);
    }
#pragma unroll
    for (int o = 32; o; o >>= 1) mx = fmaxf(mx, __shfl_xor(mx, o));
    float sum = 0.f;
    float ev[4];
#pragma unroll
    for (int p = 0; p < 4; ++p) {
      ev[p] = __expf(sv[p] - mx);
      sum += ev[p];
    }
#pragma unroll
    for (int o = 32; o; o >>= 1) sum += __shfl_xor(sum, o);
    float rs = 1.f / sum;
#pragma unroll
    for (int p = 0; p < 4; ++p) {
      int k = p * 64 + lane;
      float a = ev[p] * rs;                 // exactly 0 for masked / k>q
      A16[wave][k] = (_Float16)a;
      if (k <= q) {
        atomicAdd(&binsT[wave][tmr[k]], a);
        atomicAdd(&binsD[wave][dmr[k]], a);
      }
    }
    for (int k2 = 256 + lane; k2 < 296; k2 += 64) A16[wave][k2] = (_Float16)0.f;
  } else {
    for (int k2 = lane; k2 < 296; k2 += 64) A16[wave][k2] = (_Float16)0.f;
  }
  // convert own-row histograms to f16 (zero-padded)
  for (int c = lane; c < 296; c += 64) {
    float tv = (c < 264) ? binsT[wave][c] : 0.f;
    float dv = (c < 264) ? binsD[wave][c] : 0.f;
    Wt16[wave][c] = (_Float16)tv;
    Wd16[wave][c] = (_Float16)dv;
  }
  __syncthreads();
  // ---- phase 3: 12 MFMA jobs (matrix 0=V,1=tV,2=dV x 4 n-tiles) ----
  if (wave < 12) {
    int mat = wave >> 2, ntile = wave & 3;
    int col = ntile * 16 + row16;            // d index 0..63
    const __fp16* Arow = (mat == 0) ? &A16[row16][0]
                        : (mat == 1) ? &Wt16[row16][0] : &Wd16[row16][0];
    const ushort* Bp;
    int nsteps;
    if (mat == 0) { Bp = Vt + (size_t)(b * Hc + h * HSc + col) * VTW; nsteps = 7; }
    else {
      const ushort* Tb = (mat == 1) ? tVt : dVt;
      Bp = Tb + (size_t)(h * HSc + col) * TTW; nsteps = 9;
    }
    f32x4 acc = {0.f, 0.f, 0.f, 0.f};
    for (int s = 0; s < nsteps; ++s) {
      int kk = s * 32 + kg * 8;
      f16x8 a = *(const f16x8*)&Arow[kk];
      f16x8 bb = *(const f16x8*)&Bp[kk];
      acc = __builtin_amdgcn_mfma_f32_16x16x32_f16(a, bb, acc, 0, 0, 0);
    }
#pragma unroll
    for (int r = 0; r < 4; ++r) Opart[mat][kg * 4 + r][col] = acc[r];
  }
  __syncthreads();
  // ---- final: sum partials + residual ----
  if (q < Lc) {
    int oi = m * Hc + h * HSc + lane;
    float o = Opart[0][wave][lane] + Opart[1][wave][lane] + Opart[2][wave][lane];
    seqs[oi] = Qn[oi] + o;
  }
}

// ---------------- fused LN2 + FFN1(relu) + FFN2 + residual + keep [+ lnf] ---
template <int FIN>
__global__ __launch_bounds__(512)
void ffn_k(float* __restrict__ seqs,
           const float* __restrict__ g, const float* __restrict__ bt,
           const ushort* __restrict__ W1_16, const float* __restrict__ b1,
           const ushort* __restrict__ W2_16, const float* __restrict__ b2,
           const int* __restrict__ logs,
           const float* __restrict__ lnf_g, const float* __restrict__ lnf_b,
           float* __restrict__ dout) {
  __shared__ __fp16 Xl[16][LDH];
  __shared__ __fp16 Hl[16][LDH];
  __shared__ __fp16 Wl[128][LDH];
  __shared__ float Ol[16][Hc];
  int m0 = blockIdx.x * 16;
  int t = threadIdx.x;
  {
    int r = t >> 5, c0 = (t & 31) * 8;
    const float* xr = &seqs[(m0 + r) * Hc + c0];
    float4 v0 = *(const float4*)&xr[0];
    float4 v1 = *(const float4*)&xr[4];
    float s = v0.x + v0.y + v0.z + v0.w + v1.x + v1.y + v1.z + v1.w;
    float q = v0.x*v0.x + v0.y*v0.y + v0.z*v0.z + v0.w*v0.w
            + v1.x*v1.x + v1.y*v1.y + v1.z*v1.z + v1.w*v1.w;
#pragma unroll
    for (int o = 1; o < 32; o <<= 1) { s += __shfl_xor(s, o); q += __shfl_xor(q, o); }
    float mean = s * (1.f / Hc);
    float var = q * (1.f / Hc) - mean * mean;
    float rstd = 1.f / sqrtf(var + 1e-8f);
    float tmp[8] = {v0.x,v0.y,v0.z,v0.w,v1.x,v1.y,v1.z,v1.w};
    float nv[8];
#pragma unroll
    for (int j = 0; j < 8; ++j)
      nv[j] = (tmp[j] - mean) * rstd * g[c0 + j] + bt[c0 + j];
#pragma unroll
    for (int j = 0; j < 8; j += 2)
      *(h2*)&Xl[r][c0 + j] = __builtin_amdgcn_cvt_pkrtz(nv[j], nv[j + 1]);
  }
  int wave = t >> 6, lane = t & 63;
  int row = lane & 15, kg = lane >> 4;
#pragma unroll
  for (int ch = 0; ch < 2; ++ch) {
    __syncthreads();
    for (int i = t; i < 4096; i += 512) {
      int r = i >> 5, c = (i & 31) * 8;
      uint4 v = *(const uint4*)&W1_16[(ch * 128 + r) * Hc + c];
      *(uint4*)&Wl[r][c] = v;
    }
    __syncthreads();
    int bn = wave * 16 + row;
    f32x4 acc = {0.f, 0.f, 0.f, 0.f};
#pragma unroll
    for (int k0 = 0; k0 < Hc; k0 += 32) {
      int kk = k0 + kg * 8;
      f16x8 a = *(const f16x8*)&Xl[row][kk];
      f16x8 bb = *(const f16x8*)&Wl[bn][kk];
      acc = __builtin_amdgcn_mfma_f32_16x16x32_f16(a, bb, acc, 0, 0, 0);
    }
    int coln = ch * 128 + wave * 16 + row;
    float bv = b1[coln];
#pragma unroll
    for (int r = 0; r < 4; ++r) {
      float v = fmaxf(acc[r] + bv, 0.f);
      Hl[kg * 4 + r][coln] = (_Float16)v;
    }
  }
#pragma unroll
  for (int ch = 0; ch < 2; ++ch) {
    __syncthreads();
    for (int i = t; i < 4096; i += 512) {
      int r = i >> 5, c = (i & 31) * 8;
      uint4 v = *(const uint4*)&W2_16[(ch * 128 + r) * Hc + c];
      *(uint4*)&Wl[r][c] = v;
    }
    __syncthreads();
    int bn = wave * 16 + row;
    f32x4 acc = {0.f, 0.f, 0.f, 0.f};
#pragma unroll
    for (int k0 = 0; k0 < Hc; k0 += 32) {
      int kk = k0 + kg * 8;
      f16x8 a = *(const f16x8*)&Hl[row][kk];
      f16x8 bb = *(const f16x8*)&Wl[bn][kk];
      acc = __builtin_amdgcn_mfma_f32_16x16x32_f16(a, bb, acc, 0, 0, 0);
    }
    int coln = ch * 128 + wave * 16 + row;
    float bv = b2[coln];
#pragma unroll
    for (int r = 0; r < 4; ++r) {
      int mrow = kg * 4 + r;
      int m = m0 + mrow;
      float keep = (logs[m] != 0) ? 1.f : 0.f;
      float xv = h2f(__builtin_bit_cast(ushort, Xl[mrow][coln]));
      float val = (acc[r] + bv + xv) * keep;
      if (FIN) Ol[mrow][coln] = val;
      else     seqs[m * Hc + coln] = val;
    }
  }
  if (FIN) {
    __syncthreads();
    int r = t >> 5, c0 = (t & 31) * 8;
    float v[8];
#pragma unroll
    for (int j = 0; j < 8; ++j) v[j] = Ol[r][c0 + j];
    float s = 0.f, q = 0.f;
#pragma unroll
    for (int j = 0; j < 8; ++j) { s += v[j]; q += v[j] * v[j]; }
#pragma unroll
    for (int o = 1; o < 32; o <<= 1) { s += __shfl_xor(s, o); q += __shfl_xor(q, o); }
    float mean = s * (1.f / Hc);
    float var = q * (1.f / Hc) - mean * mean;
    float rstd = 1.f / sqrtf(var + 1e-8f);
#pragma unroll
    for (int j = 0; j < 8; ++j)
      dout[(m0 + r) * Hc + c0 + j] = (v[j] - mean) * rstd * lnf_g[c0 + j] + lnf_b[c0 + j];
  }
}

extern "C" void kernel_launch(void* const* d_in, const int* in_sizes, int n_in,
                              void* d_out, int out_size, void* d_ws, size_t ws_size,
                              hipStream_t stream) {
  const int* logs = (const int*)d_in[0];
  const int* tm   = (const int*)d_in[1];
  const int* dm   = (const int*)d_in[2];
  const float* item = (const float*)d_in[3];
  const float* pK = (const float*)d_in[4];
  const float* pV = (const float*)d_in[5];
  const float* tK = (const float*)d_in[6];
  const float* tV = (const float*)d_in[7];
  const float* dK = (const float*)d_in[8];
  const float* dV = (const float*)d_in[9];
  const float* ln1_g = (const float*)d_in[10];
  const float* ln1_b = (const float*)d_in[11];
  const float* Wq = (const float*)d_in[12];
  const float* bq = (const float*)d_in[13];
  const float* Wk = (const float*)d_in[14];
  const float* bk = (const float*)d_in[15];
  const float* Wv = (const float*)d_in[16];
  const float* bv = (const float*)d_in[17];
  const float* ln2_g = (const float*)d_in[18];
  const float* ln2_b = (const float*)d_in[19];
  const float* W1 = (const float*)d_in[20];
  const float* b1 = (const float*)d_in[21];
  const float* W2 = (const float*)d_in[22];
  const float* b2 = (const float*)d_in[23];
  const float* lnf_g = (const float*)d_in[24];
  const float* lnf_b = (const float*)d_in[25];

  const int NROW = Mtot * Hc;          // 204800 floats
  float* ws = (float*)d_ws;
  float* sSeqs = ws + 0 * NROW;
  float* sQn   = ws + 1 * NROW;
  ushort* Q16  = (ushort*)(ws + 2 * NROW);
  ushort* K16  = Q16 + NROW;
  ushort* w16  = (ushort*)(ws + 4 * NROW);   // 5*WN + 4*TN + 2*Hc*TTW halves
  ushort* wq16 = w16 + 0 * WN;
  ushort* wk16 = w16 + 1 * WN;
  ushort* wv16 = w16 + 2 * WN;
  ushort* w116 = w16 + 3 * WN;
  ushort* w216 = w16 + 4 * WN;
  ushort* tK16 = w16 + 5 * WN;
  ushort* tV16 = tK16 + TN;                  // unused by attn (kept for layout)
  ushort* dK16 = tV16 + TN;
  ushort* dV16 = dK16 + TN;
  ushort* tVt  = dV16 + TN;                  // [256][TTW]
  ushort* dVt  = tVt + Hc * TTW;
  ushort* Vt   = dVt + Hc * TTW;             // [4][256][VTW]

  dim3 gC(64, 11);
  cvtw_k<<<gC, 256, 0, stream>>>(Wq, Wk, Wv, W1, W2, tK, tV, dK, dV, w16);

  dim3 gQKV(Mtot / 16, 12);
  dim3 ga(NHc, Bc, 16);
  const int HHh = Hc * Hc;
  for (int i = 0; i < NBc; ++i) {
    mmqkv_k<<<gQKV, 256, 0, stream>>>(sSeqs, item, logs, (i == 0) ? 1 : 0,
                                      ln1_g + i * Hc, ln1_b + i * Hc,
                                      wq16 + i * HHh, wk16 + i * HHh, wv16 + i * HHh,
                                      bq + i * Hc, bk + i * Hc, bv + i * Hc,
                                      pK, pV, sQn, Q16, K16, Vt);
    attn_k<<<ga, 1024, 0, stream>>>(Q16, K16, Vt,
                                    tK16, dK16, tVt, dVt,
                                    tm, dm, logs, sQn, sSeqs);
    if (i == 0)
      ffn_k<0><<<Mtot / 16, 512, 0, stream>>>(sSeqs, ln2_g + i * Hc, ln2_b + i * Hc,
                                              w116 + i * HHh, b1 + i * Hc,
                                              w216 + i * HHh, b2 + i * Hc, logs,
                                              nullptr, nullptr, nullptr);
    else
      ffn_k<1><<<Mtot / 16, 512, 0, stream>>>(sSeqs, ln2_g + i * Hc, ln2_b + i * Hc,
                                              w116 + i * HHh, b1 + i * Hc,
                                              w216 + i * HHh, b2 + i * Hc, logs,
                                              lnf_g, lnf_b, (float*)d_out);
  }
}